// Round 1
// baseline (676.185 us; speedup 1.0000x reference)
//
#include <hip/hip_runtime.h>
#include <math.h>

// ---------------------------------------------------------------------------
// Problem: B=4, L=4096, D=P=256, tau=0.5
// out = (1/8) * sum_{b,l} [ log(S1-e^2) + log(S2-e^2) - 4*d[b,l] ]
//   S[b,q] = sum_{m<2L} exp(2 * Zhat[b,q].Zhat[b,m]),  Zhat = [z1n; z2n]
// R12: SYMMETRIC gram. exp(G) is symmetric -> compute only upper-triangle
// 128x128 tiles (2080/batch vs 4096); off-diag tiles feed BOTH row-sums and
// col-sums. Halves MFMA + exp work. One tile per block (grid 8320), single
// 32KB LDS B-buffer -> 5 blocks/CU (occupancy 20%->~50%). exp folded to
// native exp2: zn8 scaled by sqrt(2*log2e) so acc = 2*log2e*dot directly
// (kills one v_mul per gram element). dsum pairs now seen once -> factor
// -0.25*ln2.
// ---------------------------------------------------------------------------

typedef __attribute__((ext_vector_type(8))) short short8;
typedef __attribute__((ext_vector_type(4))) short short4v;
typedef __attribute__((ext_vector_type(4))) float float4v;
typedef __attribute__((ext_vector_type(8))) int int8v;
typedef __attribute__((ext_vector_type(4))) int int4v;

#if defined(__has_builtin)
#if __has_builtin(__builtin_amdgcn_exp2f)
#define EXP2F(x) __builtin_amdgcn_exp2f(x)
#endif
#endif
#ifndef EXP2F
#define EXP2F(x) __expf(0.69314718056f * (x))
#endif

__device__ __forceinline__ short f2bf(float f) {
    unsigned u = __builtin_bit_cast(unsigned, f);
    u += 0x7fffu + ((u >> 16) & 1u);          // RNE
    return (short)(u >> 16);
}

// manual fp32 -> fp8 e4m3fn (OCP), RNE.  |f| <= ~1.7 here.
__device__ __forceinline__ unsigned char f2fp8(float f) {
    float af = fabsf(f);
    unsigned s = (__builtin_bit_cast(unsigned, f) >> 31) << 7;
    if (af < 0.015625f) {                     // subnormal (<2^-6); 8 rolls up
        int q = (int)rintf(af * 512.0f);
        return (unsigned char)(s | (unsigned)q);
    }
    unsigned au = __builtin_bit_cast(unsigned, af);
    au += 0x7FFFFu + ((au >> 20) & 1u);       // RNE at bit 20
    int e = (int)(au >> 23) - 127;
    unsigned m = (au >> 20) & 7u;
    return (unsigned char)(s | (unsigned)((e + 7) << 3) | m);
}

__device__ __forceinline__ void gl_lds16(const void* g, void* l) {
    __builtin_amdgcn_global_load_lds(
        (const __attribute__((address_space(1))) void*)g,
        (__attribute__((address_space(3))) void*)l, 16, 0, 0);
}

// ---------------------------------------------------------------------------
// 256-thread NT-GEMM core: C[64 x 256] = A[arow0..+64, 256) * B[0..256)^T.
// 4 waves, wave w covers cols w*64..+64, all 64 rows.  Single-buffered LDS
// (lsA 8KB + lsB 32KB), K=256 in 4 tiles.  bf16 16x16x32 MFMA.
// ---------------------------------------------------------------------------
__device__ __forceinline__ void gemm256_core(
    const short* __restrict__ A, const short* __restrict__ B,
    int arow0, short* lsA, short* lsB, float4v acc[4][4])
{
    const int tid  = threadIdx.x;
    const int w    = tid >> 6;
    const int lane = tid & 63;
    const int l15  = lane & 15;

    for (int kt = 0; kt < 4; ++kt) {
        const int kbase = kt * 64;
#pragma unroll
        for (int r = 0; r < 10; ++r) {
            const int c = w * 10 + r;         // 0..39 chunks (8 A + 32 B)
            if (c < 8) {
                const int s   = c * 64 + lane;
                const int kc  = s >> 6;
                const int row = s & 63;
                gl_lds16(A + (size_t)(arow0 + row) * 256 + kbase + kc * 8,
                         lsA + (size_t)c * 512);
            } else {
                const int s   = (c - 8) * 64 + lane;
                const int kc  = s >> 8;
                const int row = s & 255;
                gl_lds16(B + (size_t)row * 256 + kbase + kc * 8,
                         lsB + (size_t)(c - 8) * 512);
            }
        }
        __syncthreads();
#pragma unroll
        for (int ks = 0; ks < 2; ++ks) {
            const int kc = ks * 4 + (lane >> 4);
            short8 af[4], bfv[4];
#pragma unroll
            for (int mi = 0; mi < 4; ++mi)
                af[mi] = *(const short8*)(lsA + ((size_t)kc * 64 + mi * 16 + l15) * 8);
#pragma unroll
            for (int ni = 0; ni < 4; ++ni)
                bfv[ni] = *(const short8*)(lsB + ((size_t)kc * 256 + w * 64 + ni * 16 + l15) * 8);
#pragma unroll
            for (int mi = 0; mi < 4; ++mi)
#pragma unroll
                for (int ni = 0; ni < 4; ++ni)
                    acc[mi][ni] = __builtin_amdgcn_mfma_f32_16x16x32_bf16(
                        af[mi], bfv[ni], acc[mi][ni], 0, 0, 0);
        }
        __syncthreads();
    }
}

// ---------------------------------------------------------------------------
// fp32 -> bf16 converters
// ---------------------------------------------------------------------------
__global__ __launch_bounds__(256) void convX_kernel(
    const float* __restrict__ X1, const float* __restrict__ X2,
    short* __restrict__ dst)
{
    int i = blockIdx.x * 256 + threadIdx.x;
    const float* src = (i < 1048576) ? X1 : X2;
    int j = i & 1048575;
    float4v v = ((const float4v*)src)[j];
    short4v o;
    o.x = f2bf(v.x); o.y = f2bf(v.y); o.z = f2bf(v.z); o.w = f2bf(v.w);
    ((short4v*)dst)[i] = o;
}

__global__ __launch_bounds__(256) void convW_kernel(
    const float* __restrict__ W1, const float* __restrict__ W2,
    short* __restrict__ d1, short* __restrict__ d2)
{
    int i = blockIdx.x * 256 + threadIdx.x;
    const float* src = (i < 16384) ? W1 : W2;
    short* dst = (i < 16384) ? d1 : d2;
    int j = i & 16383;
    float4v v = ((const float4v*)src)[j];
    short4v o;
    o.x = f2bf(v.x); o.y = f2bf(v.y); o.z = f2bf(v.z); o.w = f2bf(v.w);
    ((short4v*)dst)[j] = o;
}

// ---------------------------------------------------------------------------
// proj1: H = elu(X*W1^T + b1) bf16, 32768x256, grid 512 x 256thr (64-row tiles).
// ---------------------------------------------------------------------------
__global__ __launch_bounds__(256, 4) void proj1_kernel(
    const short* __restrict__ Xbf, const short* __restrict__ W1bf,
    const float* __restrict__ b1, short* __restrict__ Hbf)
{
    __shared__ short lsA[4096];    // 64 x 64
    __shared__ short lsB[16384];   // 256 x 64
    const int arow0 = blockIdx.x * 64;
    float4v acc[4][4];
#pragma unroll
    for (int mi = 0; mi < 4; ++mi)
#pragma unroll
        for (int ni = 0; ni < 4; ++ni)
            acc[mi][ni] = (float4v){0.f, 0.f, 0.f, 0.f};

    gemm256_core(Xbf, W1bf, arow0, lsA, lsB, acc);

    const int tid  = threadIdx.x;
    const int w    = tid >> 6;
    const int lane = tid & 63;
    const int rowbase = arow0 + (lane >> 4) * 4;
    const int colbase = w * 64 + (lane & 15);
#pragma unroll
    for (int ni = 0; ni < 4; ++ni) {
        const int col = colbase + ni * 16;
        const float bv = b1[col];
#pragma unroll
        for (int mi = 0; mi < 4; ++mi)
#pragma unroll
            for (int reg = 0; reg < 4; ++reg) {
                const int row = rowbase + mi * 16 + reg;
                float v = acc[mi][ni][reg] + bv;
                v = (v > 0.f) ? v : expm1f(v);
                Hbf[(size_t)row * 256 + col] = f2bf(v);
            }
    }
}

// ---------------------------------------------------------------------------
// proj2 + normalize fused -> zn8 = fp8(sqrt(2*log2e) * z/||z||) in
// [b][set][l][256].  Scale folded so gram acc = 2*log2e*dot (native exp2).
// 64-row tiles, grid 512 x 256thr.
// ---------------------------------------------------------------------------
__global__ __launch_bounds__(256, 4) void proj2norm_kernel(
    const short* __restrict__ Hbf, const short* __restrict__ W2bf,
    const float* __restrict__ b2, unsigned char* __restrict__ zn8)
{
    __shared__ short lsA[4096];
    __shared__ short lsB[16384];
    __shared__ float rssq[4][64];
    __shared__ float rinv[64];
    const int arow0 = blockIdx.x * 64;
    float4v acc[4][4];
#pragma unroll
    for (int mi = 0; mi < 4; ++mi)
#pragma unroll
        for (int ni = 0; ni < 4; ++ni)
            acc[mi][ni] = (float4v){0.f, 0.f, 0.f, 0.f};

    gemm256_core(Hbf, W2bf, arow0, lsA, lsB, acc);

    const int tid  = threadIdx.x;
    const int w    = tid >> 6;
    const int lane = tid & 63;
    const int quad = lane >> 4;
    const int l15  = lane & 15;

#pragma unroll
    for (int ni = 0; ni < 4; ++ni) {
        const float bv = b2[w * 64 + ni * 16 + l15];
#pragma unroll
        for (int mi = 0; mi < 4; ++mi)
#pragma unroll
            for (int reg = 0; reg < 4; ++reg)
                acc[mi][ni][reg] += bv;
    }
    float ps[4][4];
#pragma unroll
    for (int mi = 0; mi < 4; ++mi)
#pragma unroll
        for (int reg = 0; reg < 4; ++reg) {
            float s = 0.f;
#pragma unroll
            for (int ni = 0; ni < 4; ++ni) {
                float v = acc[mi][ni][reg];
                s += v * v;
            }
            s += __shfl_xor(s, 1); s += __shfl_xor(s, 2);
            s += __shfl_xor(s, 4); s += __shfl_xor(s, 8);
            ps[mi][reg] = s;
        }
    if (l15 == 0) {
#pragma unroll
        for (int mi = 0; mi < 4; ++mi)
#pragma unroll
            for (int reg = 0; reg < 4; ++reg)
                rssq[w][mi * 16 + quad * 4 + reg] = ps[mi][reg];
    }
    __syncthreads();
    if (tid < 64) {
        float ssq = rssq[0][tid] + rssq[1][tid] + rssq[2][tid] + rssq[3][tid];
        // sqrt(2*log2e) folded in: gram acc becomes 2*log2e*dot directly
        rinv[tid] = 1.69864360f / fmaxf(sqrtf(ssq), 1e-12f);
    }
    __syncthreads();

    const int r0  = arow0;                 // multiple of 64
    const int set = r0 >> 14;
    const int bb  = (r0 >> 12) & 3;
    const int l0  = r0 & 4095;
    unsigned char* dst = zn8 + ((size_t)(bb * 2 + set) * 4096 + l0) * 256;
    const int colbase = w * 64 + l15;
#pragma unroll
    for (int mi = 0; mi < 4; ++mi)
#pragma unroll
        for (int reg = 0; reg < 4; ++reg) {
            const int rl = mi * 16 + quad * 4 + reg;
            const float inv = rinv[rl];
#pragma unroll
            for (int ni = 0; ni < 4; ++ni)
                dst[(size_t)rl * 256 + colbase + ni * 16] =
                    f2fp8(acc[mi][ni][reg] * inv);
        }
}

// ---------------------------------------------------------------------------
// FP8 symmetric flash-gram R12: grid 8320 x 256thr (4 waves, 2wm x 2wn),
// 32KB LDS -> 5 blocks/CU.  Block = one upper-triangle 128x128 tile (ti,tj),
// tj >= ti, per batch 2080 tiles.  Off-diag tiles add exp-sums to BOTH row
// stripes ti (row-sums) and tj (col-sums, symmetry).  Diag tiles: row-sums
// only.  Cross tiles (tj==ti+32) extract the (q,q+4096) dot pairs once.
// A-frags in regs (fp8, 64 VGPR).  acc = 2*log2e*dot (scale in zn8);
// epilogue native exp2 (v_exp_f32).
// ---------------------------------------------------------------------------
#if defined(__has_builtin)
#if __has_builtin(__builtin_amdgcn_mfma_scale_f32_16x16x128_f8f6f4)
#define HAVE_MX 1
#endif
#endif

__global__ __launch_bounds__(256, 5) void gram_fp8_sym_kernel(
    const unsigned char* __restrict__ zn8, float* __restrict__ S,
    float* __restrict__ out)
{
    __shared__ unsigned char lsB[32768];      // [kp 0..15][col 0..127][16B]

    const int bx    = blockIdx.x;             // 0..8319
    const int xcd   = bx & 7;                 // batch -> XCD pair {2b,2b+1}
    const int batch = xcd >> 1;
    const int t     = (bx >> 3) * 2 + (xcd & 1);   // 0..2079 triangular index

    // decode t -> (ti,tj), 0 <= ti <= tj < 64; C(i) = 64i - i(i-1)/2
    int ti = (int)((129.0f - sqrtf((float)(16641 - 8 * t))) * 0.5f);
    if (ti < 0) ti = 0;
    if (ti > 63) ti = 63;
    while (64 * (ti + 1) - ((ti + 1) * ti) / 2 <= t) ++ti;
    while (64 * ti - (ti * (ti - 1)) / 2 > t) --ti;
    const int tj = ti + (t - (64 * ti - (ti * (ti - 1)) / 2));

    const unsigned char* Z = zn8 + (size_t)batch * 2097152;
    const int q0 = ti * 128;                  // A row base (within batch)
    const int c0 = tj * 128;                  // B col base
    const bool offdiag = (tj > ti);
    const bool cross   = (tj == ti + 32);     // holds (q, q+4096) pairs

    const int tid  = threadIdx.x;
    const int w    = tid >> 6;
    const int lane = tid & 63;
    const int wm   = w & 1;                   // 64-row band
    const int wn   = w >> 1;                  // 64-col band
    const int quad = lane >> 4;
    const int l15  = lane & 15;

    // ---- stage B tile (128 cols x 256B = 32KB) into LDS
    {
        const unsigned char* Bb = Z + (size_t)c0 * 256;
#pragma unroll
        for (int r = 0; r < 8; ++r) {
            const int c   = w * 8 + r;        // 0..31 chunks
            const int u   = c * 64 + lane;
            const int kp  = u >> 7;
            const int col = u & 127;
            gl_lds16(Bb + (size_t)col * 256 + kp * 16, &lsB[(size_t)c * 1024]);
        }
    }

    float4v acc[4][4];
#pragma unroll
    for (int mi = 0; mi < 4; ++mi)
#pragma unroll
        for (int ni = 0; ni < 4; ++ni)
            acc[mi][ni] = (float4v){0.f, 0.f, 0.f, 0.f};

#ifdef HAVE_MX
    // ---- A frags: 32 contiguous k-bytes (k = quad*32..+32) per (mi, ks)
    int8v afr[4][2];
    {
        const unsigned char* Ab = Z + (size_t)(q0 + wm * 64) * 256;
#pragma unroll
        for (int mi = 0; mi < 4; ++mi)
#pragma unroll
            for (int ks = 0; ks < 2; ++ks) {
                const unsigned char* p = Ab + (size_t)(mi * 16 + l15) * 256
                                         + ks * 128 + quad * 32;
                int4v lo = *(const int4v*)p;
                int4v hi = *(const int4v*)(p + 16);
                afr[mi][ks] = __builtin_shufflevector(lo, hi, 0,1,2,3,4,5,6,7);
            }
    }

    __syncthreads();

    {
        const unsigned char* lb = &lsB[0];
#pragma unroll
        for (int ks = 0; ks < 2; ++ks) {
            const int kp0 = ks * 8 + quad * 2;
            int8v bfv[4];
#pragma unroll
            for (int ni = 0; ni < 4; ++ni) {
                const unsigned char* p = lb +
                    ((size_t)kp0 * 128 + wn * 64 + ni * 16 + l15) * 16;
                int4v lo = *(const int4v*)p;
                int4v hi = *(const int4v*)(p + 2048);    // kp0+1 slot
                bfv[ni] = __builtin_shufflevector(lo, hi, 0,1,2,3,4,5,6,7);
            }
#pragma unroll
            for (int mi = 0; mi < 4; ++mi)
#pragma unroll
                for (int ni = 0; ni < 4; ++ni)
                    acc[mi][ni] = __builtin_amdgcn_mfma_scale_f32_16x16x128_f8f6f4(
                        afr[mi][ks], bfv[ni], acc[mi][ni],
                        0, 0,                     // cbsz=E4M3, blgp=E4M3
                        0, 0x7F7F7F7F,            // scale A = 1.0
                        0, 0x7F7F7F7F);           // scale B = 1.0
        }
    }
#else
    // ---- fallback: non-scaled 16x16x32 fp8, same shape
    long afr[4][8];
    {
        const unsigned char* Ab = Z + (size_t)(q0 + wm * 64) * 256;
#pragma unroll
        for (int mi = 0; mi < 4; ++mi)
#pragma unroll
            for (int kc = 0; kc < 8; ++kc)
                afr[mi][kc] = *(const long*)(Ab + (size_t)(mi * 16 + l15) * 256
                                             + kc * 32 + quad * 8);
    }
    __syncthreads();
    {
        const unsigned char* lb = &lsB[0];
#pragma unroll
        for (int kc = 0; kc < 8; ++kc) {
            const int kseg = kc * 4 + quad;
            const int kp   = kseg >> 1;
            const int hf   = kseg & 1;
            long bfv[4];
#pragma unroll
            for (int ni = 0; ni < 4; ++ni)
                bfv[ni] = *(const long*)(lb +
                    ((size_t)kp * 128 + wn * 64 + ni * 16 + l15) * 16 + hf * 8);
#pragma unroll
            for (int mi = 0; mi < 4; ++mi)
#pragma unroll
                for (int ni = 0; ni < 4; ++ni)
                    acc[mi][ni] = __builtin_amdgcn_mfma_f32_16x16x32_fp8_fp8(
                        afr[mi][kc], bfv[ni], acc[mi][ni], 0, 0, 0);
        }
    }
#endif

    // ---- cross-diagonal dot extraction (raw acc, BEFORE exp)
    float dsum = 0.f;
    if (cross) {
#pragma unroll
        for (int mi = 0; mi < 4; ++mi)
#pragma unroll
            for (int ni = 0; ni < 4; ++ni)
#pragma unroll
                for (int reg = 0; reg < 4; ++reg) {
                    const int r = wm * 64 + mi * 16 + quad * 4 + reg;
                    const int c = wn * 64 + ni * 16 + l15;
                    if (r == c) dsum += acc[mi][ni][reg];
                }
    }

    // ---- exp2 in place (acc already = 2*log2e*dot via zn8 scaling)
#pragma unroll
    for (int mi = 0; mi < 4; ++mi)
#pragma unroll
        for (int ni = 0; ni < 4; ++ni)
#pragma unroll
            for (int reg = 0; reg < 4; ++reg)
                acc[mi][ni][reg] = EXP2F(acc[mi][ni][reg]);

    // ---- row sums (rows q0 + wm*64 + ...), both wn waves contribute halves
    {
        float* Sr = S + (size_t)batch * 8192 + q0 + wm * 64;
#pragma unroll
        for (int mi = 0; mi < 4; ++mi)
#pragma unroll
            for (int reg = 0; reg < 4; ++reg) {
                float s = acc[mi][0][reg] + acc[mi][1][reg]
                        + acc[mi][2][reg] + acc[mi][3][reg];
                s += __shfl_xor(s, 1); s += __shfl_xor(s, 2);
                s += __shfl_xor(s, 4); s += __shfl_xor(s, 8);
                if (l15 == 0)
                    atomicAdd(&Sr[mi * 16 + quad * 4 + reg], s);
            }
    }

    // ---- col sums = symmetric row sums for stripe tj (off-diag tiles only)
    if (offdiag) {
        float* Sc = S + (size_t)batch * 8192 + c0 + wn * 64;
#pragma unroll
        for (int ni = 0; ni < 4; ++ni) {
            float s = 0.f;
#pragma unroll
            for (int mi = 0; mi < 4; ++mi)
#pragma unroll
                for (int reg = 0; reg < 4; ++reg)
                    s += acc[mi][ni][reg];
            s += __shfl_xor(s, 16); s += __shfl_xor(s, 32);
            if (quad == 0)
                atomicAdd(&Sc[ni * 16 + l15], s);
        }
    }

    // ---- dsum: each (q,q+4096) pair seen ONCE; dv = 2*log2e * sum(d)
    // need -0.5*sum(d) -> factor -0.25*ln2
    if (cross) {
        float dv = dsum;
        dv += __shfl_xor(dv, 1);  dv += __shfl_xor(dv, 2);
        dv += __shfl_xor(dv, 4);  dv += __shfl_xor(dv, 8);
        dv += __shfl_xor(dv, 16); dv += __shfl_xor(dv, 32);
        if (lane == 0)
            atomicAdd(out, -0.17328680f * dv);
    }
}

// ---------------------------------------------------------------------------
// final: out += 0.125 * sum_{32768} log(S - e^2)
// ---------------------------------------------------------------------------
__global__ __launch_bounds__(256) void final_log_kernel(
    const float* __restrict__ S, float* __restrict__ out)
{
    __shared__ float red[4];
    const int tid  = threadIdx.x;
    const int w    = tid >> 6;
    const int lane = tid & 63;
    const float E2 = 7.3890560989306495f;
    float acc = 0.f;
    for (int i = blockIdx.x * 256 + tid; i < 32768; i += gridDim.x * 256)
        acc += logf(S[i] - E2);
    acc += __shfl_xor(acc, 1);  acc += __shfl_xor(acc, 2);
    acc += __shfl_xor(acc, 4);  acc += __shfl_xor(acc, 8);
    acc += __shfl_xor(acc, 16); acc += __shfl_xor(acc, 32);
    if (lane == 0) red[w] = acc;
    __syncthreads();
    if (tid == 0)
        atomicAdd(out, 0.125f * (red[0] + red[1] + red[2] + red[3]));
}

// ---------------------------------------------------------------------------
// Workspace (bytes), total ~34 MB:
//   [0,       131072)  S (4*8192 fp32)
//   [131072,  262144)  W1bf
//   [262144,  393216)  W2bf
//   [393216, 17170432) Xbf (bf16, 16.7MB) / zn8 (fp8, first 8.4MB; aliased)
//   [17170432,33947648) Hbf
// ---------------------------------------------------------------------------
extern "C" void kernel_launch(void* const* d_in, const int* in_sizes, int n_in,
                              void* d_out, int out_size, void* d_ws, size_t ws_size,
                              hipStream_t stream)
{
    const float* X1 = (const float*)d_in[0];
    const float* X2 = (const float*)d_in[1];
    const float* W1 = (const float*)d_in[2];
    const float* b1 = (const float*)d_in[3];
    const float* W2 = (const float*)d_in[4];
    const float* b2 = (const float*)d_in[5];

    char* ws = (char*)d_ws;
    float* S    = (float*)(ws + 0);
    short* W1bf = (short*)(ws + 131072);
    short* W2bf = (short*)(ws + 262144);
    short* Xbf  = (short*)(ws + 393216);
    unsigned char* zn8 = (unsigned char*)(ws + 393216);
    short* Hbf  = (short*)(ws + 17170432);

    hipMemsetAsync(S, 0, 131072, stream);
    hipMemsetAsync(d_out, 0, sizeof(float), stream);

    convW_kernel<<<128, 256, 0, stream>>>(W1, W2, W1bf, W2bf);
    convX_kernel<<<8192, 256, 0, stream>>>(X1, X2, Xbf);
    proj1_kernel<<<512, 256, 0, stream>>>(Xbf, W1bf, b1, Hbf);
    proj2norm_kernel<<<512, 256, 0, stream>>>(Hbf, W2bf, b2, zn8);
    gram_fp8_sym_kernel<<<8320, 256, 0, stream>>>(zn8, S, (float*)d_out);
    final_log_kernel<<<64, 256, 0, stream>>>(S, (float*)d_out);
}

// Round 2
// 367.712 us; speedup vs baseline: 1.8389x; 1.8389x over previous
//
#include <hip/hip_runtime.h>
#include <math.h>

// ---------------------------------------------------------------------------
// Problem: B=4, L=4096, D=P=256, tau=0.5
// out = (1/8) * sum_{b,l} [ log(S1-e^2) + log(S2-e^2) - 4*d[b,l] ]
//   S[b,q] = sum_{m<2L} exp(2 * Zhat[b,q].Zhat[b,m]),  Zhat = [z1n; z2n]
// R13: R12's symmetric gram (upper-triangle 128x128 tiles, 2080/batch) with
// the launch-bounds spill fixed.  R12's __launch_bounds__(256,5) forced a
// ~100-reg budget on a ~168-reg kernel -> acc/afr spilled to scratch
// (VGPR 48, 2.1 GB HBM spill traffic, 551 us).  Revert to (256,2): actual
// usage ~168 regs gives 3 waves/SIMD at runtime anyway, and 32KB LDS allows
// it (R11 was LDS-limited to 2 at 64KB).  Everything else unchanged:
// off-diag tiles feed row-sums AND col-sums (symmetry -> half the MFMA+exp),
// acc = 2*log2e*dot (scale folded into zn8) -> native exp2 epilogue,
// cross tiles (tj==ti+32) extract (q,q+4096) dots once -> factor -0.25*ln2.
// ---------------------------------------------------------------------------

typedef __attribute__((ext_vector_type(8))) short short8;
typedef __attribute__((ext_vector_type(4))) short short4v;
typedef __attribute__((ext_vector_type(4))) float float4v;
typedef __attribute__((ext_vector_type(8))) int int8v;
typedef __attribute__((ext_vector_type(4))) int int4v;

#if defined(__has_builtin)
#if __has_builtin(__builtin_amdgcn_exp2f)
#define EXP2F(x) __builtin_amdgcn_exp2f(x)
#endif
#endif
#ifndef EXP2F
#define EXP2F(x) __expf(0.69314718056f * (x))
#endif

__device__ __forceinline__ short f2bf(float f) {
    unsigned u = __builtin_bit_cast(unsigned, f);
    u += 0x7fffu + ((u >> 16) & 1u);          // RNE
    return (short)(u >> 16);
}

// manual fp32 -> fp8 e4m3fn (OCP), RNE.  |f| <= ~1.7 here.
__device__ __forceinline__ unsigned char f2fp8(float f) {
    float af = fabsf(f);
    unsigned s = (__builtin_bit_cast(unsigned, f) >> 31) << 7;
    if (af < 0.015625f) {                     // subnormal (<2^-6); 8 rolls up
        int q = (int)rintf(af * 512.0f);
        return (unsigned char)(s | (unsigned)q);
    }
    unsigned au = __builtin_bit_cast(unsigned, af);
    au += 0x7FFFFu + ((au >> 20) & 1u);       // RNE at bit 20
    int e = (int)(au >> 23) - 127;
    unsigned m = (au >> 20) & 7u;
    return (unsigned char)(s | (unsigned)((e + 7) << 3) | m);
}

__device__ __forceinline__ void gl_lds16(const void* g, void* l) {
    __builtin_amdgcn_global_load_lds(
        (const __attribute__((address_space(1))) void*)g,
        (__attribute__((address_space(3))) void*)l, 16, 0, 0);
}

// ---------------------------------------------------------------------------
// 256-thread NT-GEMM core: C[64 x 256] = A[arow0..+64, 256) * B[0..256)^T.
// 4 waves, wave w covers cols w*64..+64, all 64 rows.  Single-buffered LDS
// (lsA 8KB + lsB 32KB), K=256 in 4 tiles.  bf16 16x16x32 MFMA.
// ---------------------------------------------------------------------------
__device__ __forceinline__ void gemm256_core(
    const short* __restrict__ A, const short* __restrict__ B,
    int arow0, short* lsA, short* lsB, float4v acc[4][4])
{
    const int tid  = threadIdx.x;
    const int w    = tid >> 6;
    const int lane = tid & 63;
    const int l15  = lane & 15;

    for (int kt = 0; kt < 4; ++kt) {
        const int kbase = kt * 64;
#pragma unroll
        for (int r = 0; r < 10; ++r) {
            const int c = w * 10 + r;         // 0..39 chunks (8 A + 32 B)
            if (c < 8) {
                const int s   = c * 64 + lane;
                const int kc  = s >> 6;
                const int row = s & 63;
                gl_lds16(A + (size_t)(arow0 + row) * 256 + kbase + kc * 8,
                         lsA + (size_t)c * 512);
            } else {
                const int s   = (c - 8) * 64 + lane;
                const int kc  = s >> 8;
                const int row = s & 255;
                gl_lds16(B + (size_t)row * 256 + kbase + kc * 8,
                         lsB + (size_t)(c - 8) * 512);
            }
        }
        __syncthreads();
#pragma unroll
        for (int ks = 0; ks < 2; ++ks) {
            const int kc = ks * 4 + (lane >> 4);
            short8 af[4], bfv[4];
#pragma unroll
            for (int mi = 0; mi < 4; ++mi)
                af[mi] = *(const short8*)(lsA + ((size_t)kc * 64 + mi * 16 + l15) * 8);
#pragma unroll
            for (int ni = 0; ni < 4; ++ni)
                bfv[ni] = *(const short8*)(lsB + ((size_t)kc * 256 + w * 64 + ni * 16 + l15) * 8);
#pragma unroll
            for (int mi = 0; mi < 4; ++mi)
#pragma unroll
                for (int ni = 0; ni < 4; ++ni)
                    acc[mi][ni] = __builtin_amdgcn_mfma_f32_16x16x32_bf16(
                        af[mi], bfv[ni], acc[mi][ni], 0, 0, 0);
        }
        __syncthreads();
    }
}

// ---------------------------------------------------------------------------
// fp32 -> bf16 converters
// ---------------------------------------------------------------------------
__global__ __launch_bounds__(256) void convX_kernel(
    const float* __restrict__ X1, const float* __restrict__ X2,
    short* __restrict__ dst)
{
    int i = blockIdx.x * 256 + threadIdx.x;
    const float* src = (i < 1048576) ? X1 : X2;
    int j = i & 1048575;
    float4v v = ((const float4v*)src)[j];
    short4v o;
    o.x = f2bf(v.x); o.y = f2bf(v.y); o.z = f2bf(v.z); o.w = f2bf(v.w);
    ((short4v*)dst)[i] = o;
}

__global__ __launch_bounds__(256) void convW_kernel(
    const float* __restrict__ W1, const float* __restrict__ W2,
    short* __restrict__ d1, short* __restrict__ d2)
{
    int i = blockIdx.x * 256 + threadIdx.x;
    const float* src = (i < 16384) ? W1 : W2;
    short* dst = (i < 16384) ? d1 : d2;
    int j = i & 16383;
    float4v v = ((const float4v*)src)[j];
    short4v o;
    o.x = f2bf(v.x); o.y = f2bf(v.y); o.z = f2bf(v.z); o.w = f2bf(v.w);
    ((short4v*)dst)[j] = o;
}

// ---------------------------------------------------------------------------
// proj1: H = elu(X*W1^T + b1) bf16, 32768x256, grid 512 x 256thr (64-row tiles).
// ---------------------------------------------------------------------------
__global__ __launch_bounds__(256, 4) void proj1_kernel(
    const short* __restrict__ Xbf, const short* __restrict__ W1bf,
    const float* __restrict__ b1, short* __restrict__ Hbf)
{
    __shared__ short lsA[4096];    // 64 x 64
    __shared__ short lsB[16384];   // 256 x 64
    const int arow0 = blockIdx.x * 64;
    float4v acc[4][4];
#pragma unroll
    for (int mi = 0; mi < 4; ++mi)
#pragma unroll
        for (int ni = 0; ni < 4; ++ni)
            acc[mi][ni] = (float4v){0.f, 0.f, 0.f, 0.f};

    gemm256_core(Xbf, W1bf, arow0, lsA, lsB, acc);

    const int tid  = threadIdx.x;
    const int w    = tid >> 6;
    const int lane = tid & 63;
    const int rowbase = arow0 + (lane >> 4) * 4;
    const int colbase = w * 64 + (lane & 15);
#pragma unroll
    for (int ni = 0; ni < 4; ++ni) {
        const int col = colbase + ni * 16;
        const float bv = b1[col];
#pragma unroll
        for (int mi = 0; mi < 4; ++mi)
#pragma unroll
            for (int reg = 0; reg < 4; ++reg) {
                const int row = rowbase + mi * 16 + reg;
                float v = acc[mi][ni][reg] + bv;
                v = (v > 0.f) ? v : expm1f(v);
                Hbf[(size_t)row * 256 + col] = f2bf(v);
            }
    }
}

// ---------------------------------------------------------------------------
// proj2 + normalize fused -> zn8 = fp8(sqrt(2*log2e) * z/||z||) in
// [b][set][l][256].  Scale folded so gram acc = 2*log2e*dot (native exp2).
// 64-row tiles, grid 512 x 256thr.
// ---------------------------------------------------------------------------
__global__ __launch_bounds__(256, 4) void proj2norm_kernel(
    const short* __restrict__ Hbf, const short* __restrict__ W2bf,
    const float* __restrict__ b2, unsigned char* __restrict__ zn8)
{
    __shared__ short lsA[4096];
    __shared__ short lsB[16384];
    __shared__ float rssq[4][64];
    __shared__ float rinv[64];
    const int arow0 = blockIdx.x * 64;
    float4v acc[4][4];
#pragma unroll
    for (int mi = 0; mi < 4; ++mi)
#pragma unroll
        for (int ni = 0; ni < 4; ++ni)
            acc[mi][ni] = (float4v){0.f, 0.f, 0.f, 0.f};

    gemm256_core(Hbf, W2bf, arow0, lsA, lsB, acc);

    const int tid  = threadIdx.x;
    const int w    = tid >> 6;
    const int lane = tid & 63;
    const int quad = lane >> 4;
    const int l15  = lane & 15;

#pragma unroll
    for (int ni = 0; ni < 4; ++ni) {
        const float bv = b2[w * 64 + ni * 16 + l15];
#pragma unroll
        for (int mi = 0; mi < 4; ++mi)
#pragma unroll
            for (int reg = 0; reg < 4; ++reg)
                acc[mi][ni][reg] += bv;
    }
    float ps[4][4];
#pragma unroll
    for (int mi = 0; mi < 4; ++mi)
#pragma unroll
        for (int reg = 0; reg < 4; ++reg) {
            float s = 0.f;
#pragma unroll
            for (int ni = 0; ni < 4; ++ni) {
                float v = acc[mi][ni][reg];
                s += v * v;
            }
            s += __shfl_xor(s, 1); s += __shfl_xor(s, 2);
            s += __shfl_xor(s, 4); s += __shfl_xor(s, 8);
            ps[mi][reg] = s;
        }
    if (l15 == 0) {
#pragma unroll
        for (int mi = 0; mi < 4; ++mi)
#pragma unroll
            for (int reg = 0; reg < 4; ++reg)
                rssq[w][mi * 16 + quad * 4 + reg] = ps[mi][reg];
    }
    __syncthreads();
    if (tid < 64) {
        float ssq = rssq[0][tid] + rssq[1][tid] + rssq[2][tid] + rssq[3][tid];
        // sqrt(2*log2e) folded in: gram acc becomes 2*log2e*dot directly
        rinv[tid] = 1.69864360f / fmaxf(sqrtf(ssq), 1e-12f);
    }
    __syncthreads();

    const int r0  = arow0;                 // multiple of 64
    const int set = r0 >> 14;
    const int bb  = (r0 >> 12) & 3;
    const int l0  = r0 & 4095;
    unsigned char* dst = zn8 + ((size_t)(bb * 2 + set) * 4096 + l0) * 256;
    const int colbase = w * 64 + l15;
#pragma unroll
    for (int mi = 0; mi < 4; ++mi)
#pragma unroll
        for (int reg = 0; reg < 4; ++reg) {
            const int rl = mi * 16 + quad * 4 + reg;
            const float inv = rinv[rl];
#pragma unroll
            for (int ni = 0; ni < 4; ++ni)
                dst[(size_t)rl * 256 + colbase + ni * 16] =
                    f2fp8(acc[mi][ni][reg] * inv);
        }
}

// ---------------------------------------------------------------------------
// FP8 symmetric flash-gram R13: grid 8320 x 256thr (4 waves, 2wm x 2wn),
// 32KB LDS.  Block = one upper-triangle 128x128 tile (ti,tj), tj >= ti,
// per batch 2080 tiles.  Off-diag tiles add exp-sums to BOTH row stripe ti
// (row-sums) and col stripe tj (col-sums, symmetry).  Diag tiles: row-sums
// only.  Cross tiles (tj==ti+32) extract the (q,q+4096) dot pairs once.
// A-frags in regs (fp8, 64 VGPR).  acc = 2*log2e*dot (scale in zn8);
// epilogue native exp2 (v_exp_f32).
// __launch_bounds__(256,2): register budget 256 -> no spill (R12 lesson:
// (256,5) forced VGPR 48 + 2.1GB scratch traffic).  Actual ~168 regs ->
// runtime occupancy 3 blocks/CU (LDS 32KB allows 5).
// ---------------------------------------------------------------------------
#if defined(__has_builtin)
#if __has_builtin(__builtin_amdgcn_mfma_scale_f32_16x16x128_f8f6f4)
#define HAVE_MX 1
#endif
#endif

__global__ __launch_bounds__(256, 2) void gram_fp8_sym_kernel(
    const unsigned char* __restrict__ zn8, float* __restrict__ S,
    float* __restrict__ out)
{
    __shared__ unsigned char lsB[32768];      // [kp 0..15][col 0..127][16B]

    const int bx    = blockIdx.x;             // 0..8319
    const int xcd   = bx & 7;                 // batch -> XCD pair {2b,2b+1}
    const int batch = xcd >> 1;
    const int t     = (bx >> 3) * 2 + (xcd & 1);   // 0..2079 triangular index

    // decode t -> (ti,tj), 0 <= ti <= tj < 64; C(i) = 64i - i(i-1)/2
    int ti = (int)((129.0f - sqrtf((float)(16641 - 8 * t))) * 0.5f);
    if (ti < 0) ti = 0;
    if (ti > 63) ti = 63;
    while (64 * (ti + 1) - ((ti + 1) * ti) / 2 <= t) ++ti;
    while (64 * ti - (ti * (ti - 1)) / 2 > t) --ti;
    const int tj = ti + (t - (64 * ti - (ti * (ti - 1)) / 2));

    const unsigned char* Z = zn8 + (size_t)batch * 2097152;
    const int q0 = ti * 128;                  // A row base (within batch)
    const int c0 = tj * 128;                  // B col base
    const bool offdiag = (tj > ti);
    const bool cross   = (tj == ti + 32);     // holds (q, q+4096) pairs

    const int tid  = threadIdx.x;
    const int w    = tid >> 6;
    const int lane = tid & 63;
    const int wm   = w & 1;                   // 64-row band
    const int wn   = w >> 1;                  // 64-col band
    const int quad = lane >> 4;
    const int l15  = lane & 15;

    // ---- stage B tile (128 cols x 256B = 32KB) into LDS
    {
        const unsigned char* Bb = Z + (size_t)c0 * 256;
#pragma unroll
        for (int r = 0; r < 8; ++r) {
            const int c   = w * 8 + r;        // 0..31 chunks
            const int u   = c * 64 + lane;
            const int kp  = u >> 7;
            const int col = u & 127;
            gl_lds16(Bb + (size_t)col * 256 + kp * 16, &lsB[(size_t)c * 1024]);
        }
    }

    float4v acc[4][4];
#pragma unroll
    for (int mi = 0; mi < 4; ++mi)
#pragma unroll
        for (int ni = 0; ni < 4; ++ni)
            acc[mi][ni] = (float4v){0.f, 0.f, 0.f, 0.f};

#ifdef HAVE_MX
    // ---- A frags: 32 contiguous k-bytes (k = quad*32..+32) per (mi, ks)
    int8v afr[4][2];
    {
        const unsigned char* Ab = Z + (size_t)(q0 + wm * 64) * 256;
#pragma unroll
        for (int mi = 0; mi < 4; ++mi)
#pragma unroll
            for (int ks = 0; ks < 2; ++ks) {
                const unsigned char* p = Ab + (size_t)(mi * 16 + l15) * 256
                                         + ks * 128 + quad * 32;
                int4v lo = *(const int4v*)p;
                int4v hi = *(const int4v*)(p + 16);
                afr[mi][ks] = __builtin_shufflevector(lo, hi, 0,1,2,3,4,5,6,7);
            }
    }

    __syncthreads();

    {
        const unsigned char* lb = &lsB[0];
#pragma unroll
        for (int ks = 0; ks < 2; ++ks) {
            const int kp0 = ks * 8 + quad * 2;
            int8v bfv[4];
#pragma unroll
            for (int ni = 0; ni < 4; ++ni) {
                const unsigned char* p = lb +
                    ((size_t)kp0 * 128 + wn * 64 + ni * 16 + l15) * 16;
                int4v lo = *(const int4v*)p;
                int4v hi = *(const int4v*)(p + 2048);    // kp0+1 slot
                bfv[ni] = __builtin_shufflevector(lo, hi, 0,1,2,3,4,5,6,7);
            }
#pragma unroll
            for (int mi = 0; mi < 4; ++mi)
#pragma unroll
                for (int ni = 0; ni < 4; ++ni)
                    acc[mi][ni] = __builtin_amdgcn_mfma_scale_f32_16x16x128_f8f6f4(
                        afr[mi][ks], bfv[ni], acc[mi][ni],
                        0, 0,                     // cbsz=E4M3, blgp=E4M3
                        0, 0x7F7F7F7F,            // scale A = 1.0
                        0, 0x7F7F7F7F);           // scale B = 1.0
        }
    }
#else
    // ---- fallback: non-scaled 16x16x32 fp8, same shape
    long afr[4][8];
    {
        const unsigned char* Ab = Z + (size_t)(q0 + wm * 64) * 256;
#pragma unroll
        for (int mi = 0; mi < 4; ++mi)
#pragma unroll
            for (int kc = 0; kc < 8; ++kc)
                afr[mi][kc] = *(const long*)(Ab + (size_t)(mi * 16 + l15) * 256
                                             + kc * 32 + quad * 8);
    }
    __syncthreads();
    {
        const unsigned char* lb = &lsB[0];
#pragma unroll
        for (int kc = 0; kc < 8; ++kc) {
            const int kseg = kc * 4 + quad;
            const int kp   = kseg >> 1;
            const int hf   = kseg & 1;
            long bfv[4];
#pragma unroll
            for (int ni = 0; ni < 4; ++ni)
                bfv[ni] = *(const long*)(lb +
                    ((size_t)kp * 128 + wn * 64 + ni * 16 + l15) * 16 + hf * 8);
#pragma unroll
            for (int mi = 0; mi < 4; ++mi)
#pragma unroll
                for (int ni = 0; ni < 4; ++ni)
                    acc[mi][ni] = __builtin_amdgcn_mfma_f32_16x16x32_fp8_fp8(
                        afr[mi][kc], bfv[ni], acc[mi][ni], 0, 0, 0);
        }
    }
#endif

    // ---- cross-diagonal dot extraction (raw acc, BEFORE exp)
    float dsum = 0.f;
    if (cross) {
#pragma unroll
        for (int mi = 0; mi < 4; ++mi)
#pragma unroll
            for (int ni = 0; ni < 4; ++ni)
#pragma unroll
                for (int reg = 0; reg < 4; ++reg) {
                    const int r = wm * 64 + mi * 16 + quad * 4 + reg;
                    const int c = wn * 64 + ni * 16 + l15;
                    if (r == c) dsum += acc[mi][ni][reg];
                }
    }

    // ---- exp2 in place (acc already = 2*log2e*dot via zn8 scaling)
#pragma unroll
    for (int mi = 0; mi < 4; ++mi)
#pragma unroll
        for (int ni = 0; ni < 4; ++ni)
#pragma unroll
            for (int reg = 0; reg < 4; ++reg)
                acc[mi][ni][reg] = EXP2F(acc[mi][ni][reg]);

    // ---- row sums (rows q0 + wm*64 + ...), both wn waves contribute halves
    {
        float* Sr = S + (size_t)batch * 8192 + q0 + wm * 64;
#pragma unroll
        for (int mi = 0; mi < 4; ++mi)
#pragma unroll
            for (int reg = 0; reg < 4; ++reg) {
                float s = acc[mi][0][reg] + acc[mi][1][reg]
                        + acc[mi][2][reg] + acc[mi][3][reg];
                s += __shfl_xor(s, 1); s += __shfl_xor(s, 2);
                s += __shfl_xor(s, 4); s += __shfl_xor(s, 8);
                if (l15 == 0)
                    atomicAdd(&Sr[mi * 16 + quad * 4 + reg], s);
            }
    }

    // ---- col sums = symmetric row sums for stripe tj (off-diag tiles only)
    if (offdiag) {
        float* Sc = S + (size_t)batch * 8192 + c0 + wn * 64;
#pragma unroll
        for (int ni = 0; ni < 4; ++ni) {
            float s = 0.f;
#pragma unroll
            for (int mi = 0; mi < 4; ++mi)
#pragma unroll
                for (int reg = 0; reg < 4; ++reg)
                    s += acc[mi][ni][reg];
            s += __shfl_xor(s, 16); s += __shfl_xor(s, 32);
            if (quad == 0)
                atomicAdd(&Sc[ni * 16 + l15], s);
        }
    }

    // ---- dsum: each (q,q+4096) pair seen ONCE; dv = 2*log2e * sum(d)
    // need -0.5*sum(d) -> factor -0.25*ln2
    if (cross) {
        float dv = dsum;
        dv += __shfl_xor(dv, 1);  dv += __shfl_xor(dv, 2);
        dv += __shfl_xor(dv, 4);  dv += __shfl_xor(dv, 8);
        dv += __shfl_xor(dv, 16); dv += __shfl_xor(dv, 32);
        if (lane == 0)
            atomicAdd(out, -0.17328680f * dv);
    }
}

// ---------------------------------------------------------------------------
// final: out += 0.125 * sum_{32768} log(S - e^2)
// ---------------------------------------------------------------------------
__global__ __launch_bounds__(256) void final_log_kernel(
    const float* __restrict__ S, float* __restrict__ out)
{
    __shared__ float red[4];
    const int tid  = threadIdx.x;
    const int w    = tid >> 6;
    const int lane = tid & 63;
    const float E2 = 7.3890560989306495f;
    float acc = 0.f;
    for (int i = blockIdx.x * 256 + tid; i < 32768; i += gridDim.x * 256)
        acc += logf(S[i] - E2);
    acc += __shfl_xor(acc, 1);  acc += __shfl_xor(acc, 2);
    acc += __shfl_xor(acc, 4);  acc += __shfl_xor(acc, 8);
    acc += __shfl_xor(acc, 16); acc += __shfl_xor(acc, 32);
    if (lane == 0) red[w] = acc;
    __syncthreads();
    if (tid == 0)
        atomicAdd(out, 0.125f * (red[0] + red[1] + red[2] + red[3]));
}

// ---------------------------------------------------------------------------
// Workspace (bytes), total ~34 MB:
//   [0,       131072)  S (4*8192 fp32)
//   [131072,  262144)  W1bf
//   [262144,  393216)  W2bf
//   [393216, 17170432) Xbf (bf16, 16.7MB) / zn8 (fp8, first 8.4MB; aliased)
//   [17170432,33947648) Hbf
// ---------------------------------------------------------------------------
extern "C" void kernel_launch(void* const* d_in, const int* in_sizes, int n_in,
                              void* d_out, int out_size, void* d_ws, size_t ws_size,
                              hipStream_t stream)
{
    const float* X1 = (const float*)d_in[0];
    const float* X2 = (const float*)d_in[1];
    const float* W1 = (const float*)d_in[2];
    const float* b1 = (const float*)d_in[3];
    const float* W2 = (const float*)d_in[4];
    const float* b2 = (const float*)d_in[5];

    char* ws = (char*)d_ws;
    float* S    = (float*)(ws + 0);
    short* W1bf = (short*)(ws + 131072);
    short* W2bf = (short*)(ws + 262144);
    short* Xbf  = (short*)(ws + 393216);
    unsigned char* zn8 = (unsigned char*)(ws + 393216);
    short* Hbf  = (short*)(ws + 17170432);

    hipMemsetAsync(S, 0, 131072, stream);
    hipMemsetAsync(d_out, 0, sizeof(float), stream);

    convW_kernel<<<128, 256, 0, stream>>>(W1, W2, W1bf, W2bf);
    convX_kernel<<<8192, 256, 0, stream>>>(X1, X2, Xbf);
    proj1_kernel<<<512, 256, 0, stream>>>(Xbf, W1bf, b1, Hbf);
    proj2norm_kernel<<<512, 256, 0, stream>>>(Hbf, W2bf, b2, zn8);
    gram_fp8_sym_kernel<<<8320, 256, 0, stream>>>(zn8, S, (float*)d_out);
    final_log_kernel<<<64, 256, 0, stream>>>(S, (float*)d_out);
}

// Round 3
// 214.836 us; speedup vs baseline: 3.1474x; 1.7116x over previous
//
#include <hip/hip_runtime.h>
#include <math.h>

// ---------------------------------------------------------------------------
// Problem: B=4, L=4096, D=P=256, tau=0.5
// out = (1/8) * sum_{b,l} [ log(S1-e^2) + log(S2-e^2) - 4*d[b,l] ]
//   S[b,q] = sum_{m<2L} exp(2 * Zhat[b,q].Zhat[b,m]),  Zhat = [z1n; z2n]
// R14: symmetric gram, R11 pipeline. R13 post-mortem: one-tile-per-block
// exposed the full serial chain (load latency + 512 atomics/block drain,
// 4.26M atomics total, 41MB atomic write traffic) -> everything idle
// (Mfma 5.6%, VALU 12%, occ 18%). R14 restores R11's multi-tile dbuf loop:
//  - balanced triangle: pair (p, 63-p) = 65 tiles, 4 quarters -> 512 blocks,
//    ~16 tiles/block, B-tile double-buffer, A-frags reloaded once at the
//    row-stripe boundary.
//  - row-sums in regs, atomic flush 1-2x per block (R11 pattern).
//  - col-sums (symmetry) per tile: LDS cross-wave combine + NON-atomic
//    store to scratch C[b][ti][8192] (8.39MB, aliases dead Xbf tail,
//    memset'd after proj1). final_log sums S + sum_ti C before log.
//  - acc = 2*log2e*dot (scale in zn8) -> native exp2; cross tiles
//    (tj==row+32) extract (q,q+4096) dots once -> out factor -0.25*ln2.
// ---------------------------------------------------------------------------

typedef __attribute__((ext_vector_type(8))) short short8;
typedef __attribute__((ext_vector_type(4))) short short4v;
typedef __attribute__((ext_vector_type(4))) float float4v;
typedef __attribute__((ext_vector_type(8))) int int8v;
typedef __attribute__((ext_vector_type(4))) int int4v;

#if defined(__has_builtin)
#if __has_builtin(__builtin_amdgcn_exp2f)
#define EXP2F(x) __builtin_amdgcn_exp2f(x)
#endif
#endif
#ifndef EXP2F
#define EXP2F(x) __expf(0.69314718056f * (x))
#endif

__device__ __forceinline__ short f2bf(float f) {
    unsigned u = __builtin_bit_cast(unsigned, f);
    u += 0x7fffu + ((u >> 16) & 1u);          // RNE
    return (short)(u >> 16);
}

// manual fp32 -> fp8 e4m3fn (OCP), RNE.  |f| <= ~1.7 here.
__device__ __forceinline__ unsigned char f2fp8(float f) {
    float af = fabsf(f);
    unsigned s = (__builtin_bit_cast(unsigned, f) >> 31) << 7;
    if (af < 0.015625f) {                     // subnormal (<2^-6); 8 rolls up
        int q = (int)rintf(af * 512.0f);
        return (unsigned char)(s | (unsigned)q);
    }
    unsigned au = __builtin_bit_cast(unsigned, af);
    au += 0x7FFFFu + ((au >> 20) & 1u);       // RNE at bit 20
    int e = (int)(au >> 23) - 127;
    unsigned m = (au >> 20) & 7u;
    return (unsigned char)(s | (unsigned)((e + 7) << 3) | m);
}

__device__ __forceinline__ void gl_lds16(const void* g, void* l) {
    __builtin_amdgcn_global_load_lds(
        (const __attribute__((address_space(1))) void*)g,
        (__attribute__((address_space(3))) void*)l, 16, 0, 0);
}

// ---------------------------------------------------------------------------
// 256-thread NT-GEMM core: C[64 x 256] = A[arow0..+64, 256) * B[0..256)^T.
// 4 waves, wave w covers cols w*64..+64, all 64 rows.  Single-buffered LDS
// (lsA 8KB + lsB 32KB), K=256 in 4 tiles.  bf16 16x16x32 MFMA.
// ---------------------------------------------------------------------------
__device__ __forceinline__ void gemm256_core(
    const short* __restrict__ A, const short* __restrict__ B,
    int arow0, short* lsA, short* lsB, float4v acc[4][4])
{
    const int tid  = threadIdx.x;
    const int w    = tid >> 6;
    const int lane = tid & 63;
    const int l15  = lane & 15;

    for (int kt = 0; kt < 4; ++kt) {
        const int kbase = kt * 64;
#pragma unroll
        for (int r = 0; r < 10; ++r) {
            const int c = w * 10 + r;         // 0..39 chunks (8 A + 32 B)
            if (c < 8) {
                const int s   = c * 64 + lane;
                const int kc  = s >> 6;
                const int row = s & 63;
                gl_lds16(A + (size_t)(arow0 + row) * 256 + kbase + kc * 8,
                         lsA + (size_t)c * 512);
            } else {
                const int s   = (c - 8) * 64 + lane;
                const int kc  = s >> 8;
                const int row = s & 255;
                gl_lds16(B + (size_t)row * 256 + kbase + kc * 8,
                         lsB + (size_t)(c - 8) * 512);
            }
        }
        __syncthreads();
#pragma unroll
        for (int ks = 0; ks < 2; ++ks) {
            const int kc = ks * 4 + (lane >> 4);
            short8 af[4], bfv[4];
#pragma unroll
            for (int mi = 0; mi < 4; ++mi)
                af[mi] = *(const short8*)(lsA + ((size_t)kc * 64 + mi * 16 + l15) * 8);
#pragma unroll
            for (int ni = 0; ni < 4; ++ni)
                bfv[ni] = *(const short8*)(lsB + ((size_t)kc * 256 + w * 64 + ni * 16 + l15) * 8);
#pragma unroll
            for (int mi = 0; mi < 4; ++mi)
#pragma unroll
                for (int ni = 0; ni < 4; ++ni)
                    acc[mi][ni] = __builtin_amdgcn_mfma_f32_16x16x32_bf16(
                        af[mi], bfv[ni], acc[mi][ni], 0, 0, 0);
        }
        __syncthreads();
    }
}

// ---------------------------------------------------------------------------
// fp32 -> bf16 converters
// ---------------------------------------------------------------------------
__global__ __launch_bounds__(256) void convX_kernel(
    const float* __restrict__ X1, const float* __restrict__ X2,
    short* __restrict__ dst)
{
    int i = blockIdx.x * 256 + threadIdx.x;
    const float* src = (i < 1048576) ? X1 : X2;
    int j = i & 1048575;
    float4v v = ((const float4v*)src)[j];
    short4v o;
    o.x = f2bf(v.x); o.y = f2bf(v.y); o.z = f2bf(v.z); o.w = f2bf(v.w);
    ((short4v*)dst)[i] = o;
}

__global__ __launch_bounds__(256) void convW_kernel(
    const float* __restrict__ W1, const float* __restrict__ W2,
    short* __restrict__ d1, short* __restrict__ d2)
{
    int i = blockIdx.x * 256 + threadIdx.x;
    const float* src = (i < 16384) ? W1 : W2;
    short* dst = (i < 16384) ? d1 : d2;
    int j = i & 16383;
    float4v v = ((const float4v*)src)[j];
    short4v o;
    o.x = f2bf(v.x); o.y = f2bf(v.y); o.z = f2bf(v.z); o.w = f2bf(v.w);
    ((short4v*)dst)[j] = o;
}

// ---------------------------------------------------------------------------
// proj1: H = elu(X*W1^T + b1) bf16, 32768x256, grid 512 x 256thr (64-row tiles).
// ---------------------------------------------------------------------------
__global__ __launch_bounds__(256, 4) void proj1_kernel(
    const short* __restrict__ Xbf, const short* __restrict__ W1bf,
    const float* __restrict__ b1, short* __restrict__ Hbf)
{
    __shared__ short lsA[4096];    // 64 x 64
    __shared__ short lsB[16384];   // 256 x 64
    const int arow0 = blockIdx.x * 64;
    float4v acc[4][4];
#pragma unroll
    for (int mi = 0; mi < 4; ++mi)
#pragma unroll
        for (int ni = 0; ni < 4; ++ni)
            acc[mi][ni] = (float4v){0.f, 0.f, 0.f, 0.f};

    gemm256_core(Xbf, W1bf, arow0, lsA, lsB, acc);

    const int tid  = threadIdx.x;
    const int w    = tid >> 6;
    const int lane = tid & 63;
    const int rowbase = arow0 + (lane >> 4) * 4;
    const int colbase = w * 64 + (lane & 15);
#pragma unroll
    for (int ni = 0; ni < 4; ++ni) {
        const int col = colbase + ni * 16;
        const float bv = b1[col];
#pragma unroll
        for (int mi = 0; mi < 4; ++mi)
#pragma unroll
            for (int reg = 0; reg < 4; ++reg) {
                const int row = rowbase + mi * 16 + reg;
                float v = acc[mi][ni][reg] + bv;
                v = (v > 0.f) ? v : expm1f(v);
                Hbf[(size_t)row * 256 + col] = f2bf(v);
            }
    }
}

// ---------------------------------------------------------------------------
// proj2 + normalize fused -> zn8 = fp8(sqrt(2*log2e) * z/||z||) in
// [b][set][l][256].  Scale folded so gram acc = 2*log2e*dot (native exp2).
// 64-row tiles, grid 512 x 256thr.
// ---------------------------------------------------------------------------
__global__ __launch_bounds__(256, 4) void proj2norm_kernel(
    const short* __restrict__ Hbf, const short* __restrict__ W2bf,
    const float* __restrict__ b2, unsigned char* __restrict__ zn8)
{
    __shared__ short lsA[4096];
    __shared__ short lsB[16384];
    __shared__ float rssq[4][64];
    __shared__ float rinv[64];
    const int arow0 = blockIdx.x * 64;
    float4v acc[4][4];
#pragma unroll
    for (int mi = 0; mi < 4; ++mi)
#pragma unroll
        for (int ni = 0; ni < 4; ++ni)
            acc[mi][ni] = (float4v){0.f, 0.f, 0.f, 0.f};

    gemm256_core(Hbf, W2bf, arow0, lsA, lsB, acc);

    const int tid  = threadIdx.x;
    const int w    = tid >> 6;
    const int lane = tid & 63;
    const int quad = lane >> 4;
    const int l15  = lane & 15;

#pragma unroll
    for (int ni = 0; ni < 4; ++ni) {
        const float bv = b2[w * 64 + ni * 16 + l15];
#pragma unroll
        for (int mi = 0; mi < 4; ++mi)
#pragma unroll
            for (int reg = 0; reg < 4; ++reg)
                acc[mi][ni][reg] += bv;
    }
    float ps[4][4];
#pragma unroll
    for (int mi = 0; mi < 4; ++mi)
#pragma unroll
        for (int reg = 0; reg < 4; ++reg) {
            float s = 0.f;
#pragma unroll
            for (int ni = 0; ni < 4; ++ni) {
                float v = acc[mi][ni][reg];
                s += v * v;
            }
            s += __shfl_xor(s, 1); s += __shfl_xor(s, 2);
            s += __shfl_xor(s, 4); s += __shfl_xor(s, 8);
            ps[mi][reg] = s;
        }
    if (l15 == 0) {
#pragma unroll
        for (int mi = 0; mi < 4; ++mi)
#pragma unroll
            for (int reg = 0; reg < 4; ++reg)
                rssq[w][mi * 16 + quad * 4 + reg] = ps[mi][reg];
    }
    __syncthreads();
    if (tid < 64) {
        float ssq = rssq[0][tid] + rssq[1][tid] + rssq[2][tid] + rssq[3][tid];
        // sqrt(2*log2e) folded in: gram acc becomes 2*log2e*dot directly
        rinv[tid] = 1.69864360f / fmaxf(sqrtf(ssq), 1e-12f);
    }
    __syncthreads();

    const int r0  = arow0;                 // multiple of 64
    const int set = r0 >> 14;
    const int bb  = (r0 >> 12) & 3;
    const int l0  = r0 & 4095;
    unsigned char* dst = zn8 + ((size_t)(bb * 2 + set) * 4096 + l0) * 256;
    const int colbase = w * 64 + l15;
#pragma unroll
    for (int mi = 0; mi < 4; ++mi)
#pragma unroll
        for (int reg = 0; reg < 4; ++reg) {
            const int rl = mi * 16 + quad * 4 + reg;
            const float inv = rinv[rl];
#pragma unroll
            for (int ni = 0; ni < 4; ++ni)
                dst[(size_t)rl * 256 + colbase + ni * 16] =
                    f2fp8(acc[mi][ni][reg] * inv);
        }
}

// ---------------------------------------------------------------------------
// FP8 symmetric flash-gram R14: grid 512 x 256thr (4 waves, 2wm x 2wn).
// Block = (batch, pair p, quarter): pair = row-stripes {p, 63-p}, 65 tiles
// (row p: tj=p..63, then row 63-p: tj=63-p..63), quarters of 17/16/16/16.
// Double-buffered 32KB B staging; A-frags (64 VGPR fp8) reloaded once at
// the row break.  Row-sums in regs -> atomic flush per stripe.  Col-sums
// (symmetry) per off-diag tile -> LDS combine -> non-atomic store into
// Cc[batch][row][8192].  Cross tiles (tj==row+32): d-dot extraction.
// ---------------------------------------------------------------------------
#if defined(__has_builtin)
#if __has_builtin(__builtin_amdgcn_mfma_scale_f32_16x16x128_f8f6f4)
#define HAVE_MX 1
#endif
#endif

__global__ __launch_bounds__(256, 2) void gram_fp8_sym_kernel(
    const unsigned char* __restrict__ zn8, float* __restrict__ S,
    float* __restrict__ Cc, float* __restrict__ out)
{
    __shared__ unsigned char lsB[2][32768];   // [buf][kp 0..15][col 0..127][16B]
    __shared__ float ldscol[128];

    const int bx    = blockIdx.x;             // 0..511
    const int xcd   = bx & 7;                 // batch -> XCD pair {2b,2b+1}
    const int batch = xcd >> 1;
    const int sub   = (bx >> 3) * 2 + (xcd & 1);   // 0..127
    const int p     = sub >> 2;               // pair 0..31
    const int qu    = sub & 3;                // quarter
    const int u0    = (qu == 0) ? 0 : 17 + (qu - 1) * 16;
    const int u1    = u0 + ((qu == 0) ? 17 : 16);
    const int ubrk  = 64 - p;                 // first tile index of row 63-p

    const unsigned char* Z = zn8 + (size_t)batch * 2097152;

    const int tid  = threadIdx.x;
    const int w    = tid >> 6;
    const int lane = tid & 63;
    const int wm   = w & 1;                   // 64-row band
    const int wn   = w >> 1;                  // 64-col band
    const int quad = lane >> 4;
    const int l15  = lane & 15;

#define TJ_OF(u)  ((u) < ubrk ? p + (u) : (u) - 1)
#define ROW_OF(u) ((u) < ubrk ? p : 63 - p)

#define STAGE_B(t, buf)                                                       \
    {                                                                         \
        const unsigned char* Bb = Z + (size_t)(t) * 128 * 256;                \
        _Pragma("unroll")                                                     \
        for (int r = 0; r < 8; ++r) {                                         \
            const int c   = w * 8 + r;                                        \
            const int u_  = c * 64 + lane;                                    \
            const int kp  = u_ >> 7;                                          \
            const int col = u_ & 127;                                         \
            gl_lds16(Bb + (size_t)col * 256 + kp * 16,                        \
                     &lsB[buf][(size_t)c * 1024]);                            \
        }                                                                     \
    }

    float rs[4][4];
#pragma unroll
    for (int mi = 0; mi < 4; ++mi)
#pragma unroll
        for (int reg = 0; reg < 4; ++reg)
            rs[mi][reg] = 0.f;
    float dsum = 0.f;

#define FLUSH_RS(rowstripe)                                                   \
    {                                                                         \
        float* Sr = S + (size_t)batch * 8192 + (rowstripe) * 128 + wm * 64;   \
        _Pragma("unroll")                                                     \
        for (int mi = 0; mi < 4; ++mi)                                        \
            _Pragma("unroll")                                                 \
            for (int reg = 0; reg < 4; ++reg) {                               \
                float v = rs[mi][reg];                                        \
                v += __shfl_xor(v, 1); v += __shfl_xor(v, 2);                 \
                v += __shfl_xor(v, 4); v += __shfl_xor(v, 8);                 \
                if (l15 == 0)                                                 \
                    atomicAdd(&Sr[mi * 16 + quad * 4 + reg], v);              \
                rs[mi][reg] = 0.f;                                            \
            }                                                                 \
    }

    int currow = ROW_OF(u0);

#ifdef HAVE_MX
    int8v afr[4][2];
#define LOAD_A(rowstripe)                                                     \
    {                                                                         \
        const unsigned char* Ab = Z + (size_t)((rowstripe) * 128 + wm * 64) * 256; \
        _Pragma("unroll")                                                     \
        for (int mi = 0; mi < 4; ++mi)                                        \
            _Pragma("unroll")                                                 \
            for (int ks = 0; ks < 2; ++ks) {                                  \
                const unsigned char* pA = Ab + (size_t)(mi * 16 + l15) * 256  \
                                          + ks * 128 + quad * 32;             \
                int4v lo = *(const int4v*)pA;                                 \
                int4v hi = *(const int4v*)(pA + 16);                          \
                afr[mi][ks] = __builtin_shufflevector(lo, hi, 0,1,2,3,4,5,6,7); \
            }                                                                 \
    }
#else
    long afr[4][8];
#define LOAD_A(rowstripe)                                                     \
    {                                                                         \
        const unsigned char* Ab = Z + (size_t)((rowstripe) * 128 + wm * 64) * 256; \
        _Pragma("unroll")                                                     \
        for (int mi = 0; mi < 4; ++mi)                                        \
            _Pragma("unroll")                                                 \
            for (int kc = 0; kc < 8; ++kc)                                    \
                afr[mi][kc] = *(const long*)(Ab + (size_t)(mi * 16 + l15) * 256 \
                                             + kc * 32 + quad * 8);           \
    }
#endif

    LOAD_A(currow);
    STAGE_B(TJ_OF(u0), 0);
    __syncthreads();

    for (int ui = u0; ui < u1; ++ui) {
        const int buf = (ui - u0) & 1;
        const int row = ROW_OF(ui);
        const int tj  = TJ_OF(ui);
        if (row != currow) {                  // crossed into row 63-p
            FLUSH_RS(currow);
            LOAD_A(row);
            currow = row;
        }
        if (ui + 1 < u1) STAGE_B(TJ_OF(ui + 1), buf ^ 1);

        float4v acc[4][4];
#pragma unroll
        for (int mi = 0; mi < 4; ++mi)
#pragma unroll
            for (int ni = 0; ni < 4; ++ni)
                acc[mi][ni] = (float4v){0.f, 0.f, 0.f, 0.f};

        const unsigned char* lb = &lsB[buf][0];
#ifdef HAVE_MX
#pragma unroll
        for (int ks = 0; ks < 2; ++ks) {
            const int kp0 = ks * 8 + quad * 2;
            int8v bfv[4];
#pragma unroll
            for (int ni = 0; ni < 4; ++ni) {
                const unsigned char* pB = lb +
                    ((size_t)kp0 * 128 + wn * 64 + ni * 16 + l15) * 16;
                int4v lo = *(const int4v*)pB;
                int4v hi = *(const int4v*)(pB + 2048);   // kp0+1 slot
                bfv[ni] = __builtin_shufflevector(lo, hi, 0,1,2,3,4,5,6,7);
            }
#pragma unroll
            for (int mi = 0; mi < 4; ++mi)
#pragma unroll
                for (int ni = 0; ni < 4; ++ni)
                    acc[mi][ni] = __builtin_amdgcn_mfma_scale_f32_16x16x128_f8f6f4(
                        afr[mi][ks], bfv[ni], acc[mi][ni],
                        0, 0,                     // cbsz=E4M3, blgp=E4M3
                        0, 0x7F7F7F7F,            // scale A = 1.0
                        0, 0x7F7F7F7F);           // scale B = 1.0
        }
#else
#pragma unroll
        for (int kc = 0; kc < 8; ++kc) {
            const int kseg = kc * 4 + quad;
            const int kp   = kseg >> 1;
            const int hf   = kseg & 1;
            long bfv[4];
#pragma unroll
            for (int ni = 0; ni < 4; ++ni)
                bfv[ni] = *(const long*)(lb +
                    ((size_t)kp * 128 + wn * 64 + ni * 16 + l15) * 16 + hf * 8);
#pragma unroll
            for (int mi = 0; mi < 4; ++mi)
#pragma unroll
                for (int ni = 0; ni < 4; ++ni)
                    acc[mi][ni] = __builtin_amdgcn_mfma_f32_16x16x32_fp8_fp8(
                        afr[mi][kc], bfv[ni], acc[mi][ni], 0, 0, 0);
        }
#endif

        // ---- cross tile: extract (q,q+4096) dots (raw acc, BEFORE exp)
        if (tj == row + 32) {
#pragma unroll
            for (int mi = 0; mi < 4; ++mi)
#pragma unroll
                for (int ni = 0; ni < 4; ++ni)
#pragma unroll
                    for (int reg = 0; reg < 4; ++reg) {
                        const int r = wm * 64 + mi * 16 + quad * 4 + reg;
                        const int c = wn * 64 + ni * 16 + l15;
                        if (r == c) dsum += acc[mi][ni][reg];
                    }
        }

        // ---- exp2 in place (acc already = 2*log2e*dot via zn8 scaling)
#pragma unroll
        for (int mi = 0; mi < 4; ++mi)
#pragma unroll
            for (int ni = 0; ni < 4; ++ni)
#pragma unroll
                for (int reg = 0; reg < 4; ++reg)
                    acc[mi][ni][reg] = EXP2F(acc[mi][ni][reg]);

        // ---- row sums accumulate in regs
#pragma unroll
        for (int mi = 0; mi < 4; ++mi)
#pragma unroll
            for (int reg = 0; reg < 4; ++reg)
                rs[mi][reg] += acc[mi][0][reg] + acc[mi][1][reg]
                             + acc[mi][2][reg] + acc[mi][3][reg];

        // ---- col sums (symmetry): off-diagonal tiles only, non-atomic
        if (tj > row) {
            float cs[4];
#pragma unroll
            for (int ni = 0; ni < 4; ++ni) {
                float s = 0.f;
#pragma unroll
                for (int mi = 0; mi < 4; ++mi)
#pragma unroll
                    for (int reg = 0; reg < 4; ++reg)
                        s += acc[mi][ni][reg];
                s += __shfl_xor(s, 16); s += __shfl_xor(s, 32);
                cs[ni] = s;
            }
            if (wm == 0 && quad == 0) {
#pragma unroll
                for (int ni = 0; ni < 4; ++ni)
                    ldscol[wn * 64 + ni * 16 + l15] = cs[ni];
            }
            __syncthreads();
            if (wm == 1 && quad == 0) {
                float* Cd = Cc + ((size_t)batch * 64 + row) * 8192
                            + tj * 128 + wn * 64;
#pragma unroll
                for (int ni = 0; ni < 4; ++ni)
                    Cd[ni * 16 + l15] = cs[ni] + ldscol[wn * 64 + ni * 16 + l15];
            }
        }
        __syncthreads();
    }

    FLUSH_RS(currow);

    // dv = 2*log2e * sum(d);  need -0.5*sum(d) -> factor -0.25*ln2
    {
        float dv = dsum;
        dv += __shfl_xor(dv, 1);  dv += __shfl_xor(dv, 2);
        dv += __shfl_xor(dv, 4);  dv += __shfl_xor(dv, 8);
        dv += __shfl_xor(dv, 16); dv += __shfl_xor(dv, 32);
        if (lane == 0 && dv != 0.f)
            atomicAdd(out, -0.17328680f * dv);
    }
#undef STAGE_B
#undef LOAD_A
#undef FLUSH_RS
#undef TJ_OF
#undef ROW_OF
}

// ---------------------------------------------------------------------------
// final: out += 0.125 * sum_{b,q} log(S[b][q] + sum_ti Cc[b][ti][q] - e^2)
// grid 128 x 256 (one thread per (b,q)).
// ---------------------------------------------------------------------------
__global__ __launch_bounds__(256) void final_log_kernel(
    const float* __restrict__ S, const float* __restrict__ Cc,
    float* __restrict__ out)
{
    __shared__ float red[4];
    const int tid  = threadIdx.x;
    const int w    = tid >> 6;
    const int lane = tid & 63;
    const float E2 = 7.3890560989306495f;

    const int i = blockIdx.x * 256 + tid;     // 0..32767
    const int b = i >> 13;
    const int q = i & 8191;
    float s = S[i];
    const float* Cp = Cc + (size_t)b * 64 * 8192 + q;
#pragma unroll 8
    for (int ti = 0; ti < 64; ++ti)
        s += Cp[(size_t)ti * 8192];
    float acc = logf(s - E2);

    acc += __shfl_xor(acc, 1);  acc += __shfl_xor(acc, 2);
    acc += __shfl_xor(acc, 4);  acc += __shfl_xor(acc, 8);
    acc += __shfl_xor(acc, 16); acc += __shfl_xor(acc, 32);
    if (lane == 0) red[w] = acc;
    __syncthreads();
    if (tid == 0)
        atomicAdd(out, 0.125f * (red[0] + red[1] + red[2] + red[3]));
}

// ---------------------------------------------------------------------------
// Workspace (bytes), total ~34 MB:
//   [0,       131072)  S (4*8192 fp32)
//   [131072,  262144)  W1bf
//   [262144,  393216)  W2bf
//   [393216, 17170432) Xbf (bf16, 16.7MB); aliased after proj1:
//       [393216,  8781824)  zn8 (fp8, 8.39MB)
//       [8781824, 17170432) Cc  (col-sum scratch, 4*64*8192 fp32 = 8.39MB)
//   [17170432,33947648) Hbf
// ---------------------------------------------------------------------------
extern "C" void kernel_launch(void* const* d_in, const int* in_sizes, int n_in,
                              void* d_out, int out_size, void* d_ws, size_t ws_size,
                              hipStream_t stream)
{
    const float* X1 = (const float*)d_in[0];
    const float* X2 = (const float*)d_in[1];
    const float* W1 = (const float*)d_in[2];
    const float* b1 = (const float*)d_in[3];
    const float* W2 = (const float*)d_in[4];
    const float* b2 = (const float*)d_in[5];

    char* ws = (char*)d_ws;
    float* S    = (float*)(ws + 0);
    short* W1bf = (short*)(ws + 131072);
    short* W2bf = (short*)(ws + 262144);
    short* Xbf  = (short*)(ws + 393216);
    unsigned char* zn8 = (unsigned char*)(ws + 393216);
    float* Cc   = (float*)(ws + 8781824);
    short* Hbf  = (short*)(ws + 17170432);

    hipMemsetAsync(S, 0, 131072, stream);
    hipMemsetAsync(d_out, 0, sizeof(float), stream);

    convW_kernel<<<128, 256, 0, stream>>>(W1, W2, W1bf, W2bf);
    convX_kernel<<<8192, 256, 0, stream>>>(X1, X2, Xbf);
    proj1_kernel<<<512, 256, 0, stream>>>(Xbf, W1bf, b1, Hbf);
    // Xbf dead after proj1 -> zero the aliased col-sum scratch
    hipMemsetAsync(Cc, 0, 8388608, stream);
    proj2norm_kernel<<<512, 256, 0, stream>>>(Hbf, W2bf, b2, zn8);
    gram_fp8_sym_kernel<<<512, 256, 0, stream>>>(zn8, S, Cc, (float*)d_out);
    final_log_kernel<<<128, 256, 0, stream>>>(S, Cc, (float*)d_out);
}

// Round 5
// 213.748 us; speedup vs baseline: 3.1635x; 1.0051x over previous
//
#include <hip/hip_runtime.h>
#include <math.h>

// ---------------------------------------------------------------------------
// Problem: B=4, L=4096, D=P=256, tau=0.5
// out = (1/8) * sum_{b,l} [ log(S1-e^2) + log(S2-e^2) - 4*d[b,l] ]
//   S[b,q] = sum_{m<2L} exp(2 * Zhat[b,q].Zhat[b,m]),  Zhat = [z1n; z2n]
// R16 = R15 resubmitted verbatim after container infra failure.
// R15: (a) proj1+proj2norm FUSED (H stays in LDS, staged layout; kills
// 33.5MB Hbf roundtrip + 1 launch). (b) gram: col-sums stored per-(wm)
// half directly to Cc planes (128/batch) -> deletes ldscol + the 2nd
// per-tile barrier; s_setprio around MFMA cluster. (c) final_log reads
// only the 2*(q>>7) valid planes -> no Cc memset. Layout: zn8 moved to
// old Hbf region; Cc aliases Xbf (dead after fusedproj).
// ---------------------------------------------------------------------------

typedef __attribute__((ext_vector_type(8))) short short8;
typedef __attribute__((ext_vector_type(4))) short short4v;
typedef __attribute__((ext_vector_type(4))) float float4v;
typedef __attribute__((ext_vector_type(8))) int int8v;
typedef __attribute__((ext_vector_type(4))) int int4v;

#if defined(__has_builtin)
#if __has_builtin(__builtin_amdgcn_exp2f)
#define EXP2F(x) __builtin_amdgcn_exp2f(x)
#endif
#endif
#ifndef EXP2F
#define EXP2F(x) __expf(0.69314718056f * (x))
#endif

__device__ __forceinline__ short f2bf(float f) {
    unsigned u = __builtin_bit_cast(unsigned, f);
    u += 0x7fffu + ((u >> 16) & 1u);          // RNE
    return (short)(u >> 16);
}

// manual fp32 -> fp8 e4m3fn (OCP), RNE.  |f| <= ~1.7 here.
__device__ __forceinline__ unsigned char f2fp8(float f) {
    float af = fabsf(f);
    unsigned s = (__builtin_bit_cast(unsigned, f) >> 31) << 7;
    if (af < 0.015625f) {                     // subnormal (<2^-6); 8 rolls up
        int q = (int)rintf(af * 512.0f);
        return (unsigned char)(s | (unsigned)q);
    }
    unsigned au = __builtin_bit_cast(unsigned, af);
    au += 0x7FFFFu + ((au >> 20) & 1u);       // RNE at bit 20
    int e = (int)(au >> 23) - 127;
    unsigned m = (au >> 20) & 7u;
    return (unsigned char)(s | (unsigned)((e + 7) << 3) | m);
}

__device__ __forceinline__ void gl_lds16(const void* g, void* l) {
    __builtin_amdgcn_global_load_lds(
        (const __attribute__((address_space(1))) void*)g,
        (__attribute__((address_space(3))) void*)l, 16, 0, 0);
}

// ---------------------------------------------------------------------------
// 256-thread NT-GEMM core: C[64 x 256] = A[arow0..+64, 256) * B[0..256)^T.
// 4 waves, wave w covers cols w*64..+64, all 64 rows.  Single-buffered LDS
// (lsA 8KB + lsB 32KB), K=256 in 4 tiles.  bf16 16x16x32 MFMA.
// ---------------------------------------------------------------------------
__device__ __forceinline__ void gemm256_core(
    const short* __restrict__ A, const short* __restrict__ B,
    int arow0, short* lsA, short* lsB, float4v acc[4][4])
{
    const int tid  = threadIdx.x;
    const int w    = tid >> 6;
    const int lane = tid & 63;
    const int l15  = lane & 15;

    for (int kt = 0; kt < 4; ++kt) {
        const int kbase = kt * 64;
#pragma unroll
        for (int r = 0; r < 10; ++r) {
            const int c = w * 10 + r;         // 0..39 chunks (8 A + 32 B)
            if (c < 8) {
                const int s   = c * 64 + lane;
                const int kc  = s >> 6;
                const int row = s & 63;
                gl_lds16(A + (size_t)(arow0 + row) * 256 + kbase + kc * 8,
                         lsA + (size_t)c * 512);
            } else {
                const int s   = (c - 8) * 64 + lane;
                const int kc  = s >> 8;
                const int row = s & 255;
                gl_lds16(B + (size_t)row * 256 + kbase + kc * 8,
                         lsB + (size_t)(c - 8) * 512);
            }
        }
        __syncthreads();
#pragma unroll
        for (int ks = 0; ks < 2; ++ks) {
            const int kc = ks * 4 + (lane >> 4);
            short8 af[4], bfv[4];
#pragma unroll
            for (int mi = 0; mi < 4; ++mi)
                af[mi] = *(const short8*)(lsA + ((size_t)kc * 64 + mi * 16 + l15) * 8);
#pragma unroll
            for (int ni = 0; ni < 4; ++ni)
                bfv[ni] = *(const short8*)(lsB + ((size_t)kc * 256 + w * 64 + ni * 16 + l15) * 8);
#pragma unroll
            for (int mi = 0; mi < 4; ++mi)
#pragma unroll
                for (int ni = 0; ni < 4; ++ni)
                    acc[mi][ni] = __builtin_amdgcn_mfma_f32_16x16x32_bf16(
                        af[mi], bfv[ni], acc[mi][ni], 0, 0, 0);
        }
        __syncthreads();
    }
}

// ---------------------------------------------------------------------------
// fp32 -> bf16 converters
// ---------------------------------------------------------------------------
__global__ __launch_bounds__(256) void convX_kernel(
    const float* __restrict__ X1, const float* __restrict__ X2,
    short* __restrict__ dst)
{
    int i = blockIdx.x * 256 + threadIdx.x;
    const float* src = (i < 1048576) ? X1 : X2;
    int j = i & 1048575;
    float4v v = ((const float4v*)src)[j];
    short4v o;
    o.x = f2bf(v.x); o.y = f2bf(v.y); o.z = f2bf(v.z); o.w = f2bf(v.w);
    ((short4v*)dst)[i] = o;
}

__global__ __launch_bounds__(256) void convW_kernel(
    const float* __restrict__ W1, const float* __restrict__ W2,
    short* __restrict__ d1, short* __restrict__ d2)
{
    int i = blockIdx.x * 256 + threadIdx.x;
    const float* src = (i < 16384) ? W1 : W2;
    short* dst = (i < 16384) ? d1 : d2;
    int j = i & 16383;
    float4v v = ((const float4v*)src)[j];
    short4v o;
    o.x = f2bf(v.x); o.y = f2bf(v.y); o.z = f2bf(v.z); o.w = f2bf(v.w);
    ((short4v*)dst)[j] = o;
}

// ---------------------------------------------------------------------------
// fused proj: per 64-row block:
//   phase1: acc = X*W1^T (gemm256_core) -> +b1, elu -> bf16 -> lsH
//           (staged layout [p>>3][row][p&7], conflict-free phase2 reads)
//   phase2: acc = H*W2^T (A-frags from lsH, W2 staged per kt)
//   epilogue: +b2, rownorm -> zn8 = fp8(sqrt(2*log2e)*z/||z||)
// grid 512 x 256thr.  LDS ~73KB -> 2 blocks/CU.
// ---------------------------------------------------------------------------
__global__ __launch_bounds__(256, 2) void fusedproj_kernel(
    const short* __restrict__ Xbf, const short* __restrict__ W1bf,
    const float* __restrict__ b1, const short* __restrict__ W2bf,
    const float* __restrict__ b2, unsigned char* __restrict__ zn8)
{
    __shared__ short lsA[4096];    // 8KB  X staging
    __shared__ short lsB[16384];   // 32KB W1/W2 staging
    __shared__ short lsH[16384];   // 32KB H, staged layout
    __shared__ float rssq[4][64];
    __shared__ float rinv[64];

    const int arow0 = blockIdx.x * 64;
    const int tid  = threadIdx.x;
    const int w    = tid >> 6;
    const int lane = tid & 63;
    const int quad = lane >> 4;
    const int l15  = lane & 15;

    float4v acc[4][4];
#pragma unroll
    for (int mi = 0; mi < 4; ++mi)
#pragma unroll
        for (int ni = 0; ni < 4; ++ni)
            acc[mi][ni] = (float4v){0.f, 0.f, 0.f, 0.f};

    // ---- phase 1: X * W1^T
    gemm256_core(Xbf, W1bf, arow0, lsA, lsB, acc);

    // ---- epilogue 1: +b1, elu, bf16 -> lsH  (local rows 0..63)
    {
        const int rowbase = quad * 4;
        const int colbase = w * 64 + l15;
#pragma unroll
        for (int ni = 0; ni < 4; ++ni) {
            const int p  = colbase + ni * 16;
            const float bv = b1[p];
#pragma unroll
            for (int mi = 0; mi < 4; ++mi)
#pragma unroll
                for (int reg = 0; reg < 4; ++reg) {
                    const int row = rowbase + mi * 16 + reg;
                    float v = acc[mi][ni][reg] + bv;
                    v = (v > 0.f) ? v : expm1f(v);
                    lsH[(size_t)(p >> 3) * 512 + row * 8 + (p & 7)] = f2bf(v);
                }
        }
    }

    // ---- phase 2: H * W2^T  (A from lsH, B = W2 staged per kt)
#pragma unroll
    for (int mi = 0; mi < 4; ++mi)
#pragma unroll
        for (int ni = 0; ni < 4; ++ni)
            acc[mi][ni] = (float4v){0.f, 0.f, 0.f, 0.f};

    for (int kt = 0; kt < 4; ++kt) {
        const int kbase = kt * 64;
#pragma unroll
        for (int r = 0; r < 8; ++r) {
            const int c   = w * 8 + r;        // 0..31 chunks, all B
            const int s   = c * 64 + lane;
            const int kc  = s >> 8;
            const int row = s & 255;
            gl_lds16(W2bf + (size_t)row * 256 + kbase + kc * 8,
                     lsB + (size_t)c * 512);
        }
        __syncthreads();                      // kt=0: also guards lsH writes
#pragma unroll
        for (int ks = 0; ks < 2; ++ks) {
            const int kc = ks * 4 + quad;
            short8 af[4], bfv[4];
#pragma unroll
            for (int mi = 0; mi < 4; ++mi)
                af[mi] = *(const short8*)(lsH +
                    ((size_t)(kt * 8 + kc) * 64 + mi * 16 + l15) * 8);
#pragma unroll
            for (int ni = 0; ni < 4; ++ni)
                bfv[ni] = *(const short8*)(lsB +
                    ((size_t)kc * 256 + w * 64 + ni * 16 + l15) * 8);
#pragma unroll
            for (int mi = 0; mi < 4; ++mi)
#pragma unroll
                for (int ni = 0; ni < 4; ++ni)
                    acc[mi][ni] = __builtin_amdgcn_mfma_f32_16x16x32_bf16(
                        af[mi], bfv[ni], acc[mi][ni], 0, 0, 0);
        }
        __syncthreads();
    }

    // ---- epilogue 2: +b2, normalize, fp8 out (sqrt(2*log2e) folded)
#pragma unroll
    for (int ni = 0; ni < 4; ++ni) {
        const float bv = b2[w * 64 + ni * 16 + l15];
#pragma unroll
        for (int mi = 0; mi < 4; ++mi)
#pragma unroll
            for (int reg = 0; reg < 4; ++reg)
                acc[mi][ni][reg] += bv;
    }
    float ps[4][4];
#pragma unroll
    for (int mi = 0; mi < 4; ++mi)
#pragma unroll
        for (int reg = 0; reg < 4; ++reg) {
            float s = 0.f;
#pragma unroll
            for (int ni = 0; ni < 4; ++ni) {
                float v = acc[mi][ni][reg];
                s += v * v;
            }
            s += __shfl_xor(s, 1); s += __shfl_xor(s, 2);
            s += __shfl_xor(s, 4); s += __shfl_xor(s, 8);
            ps[mi][reg] = s;
        }
    if (l15 == 0) {
#pragma unroll
        for (int mi = 0; mi < 4; ++mi)
#pragma unroll
            for (int reg = 0; reg < 4; ++reg)
                rssq[w][mi * 16 + quad * 4 + reg] = ps[mi][reg];
    }
    __syncthreads();
    if (tid < 64) {
        float ssq = rssq[0][tid] + rssq[1][tid] + rssq[2][tid] + rssq[3][tid];
        rinv[tid] = 1.69864360f / fmaxf(sqrtf(ssq), 1e-12f);
    }
    __syncthreads();

    const int r0  = arow0;                 // multiple of 64
    const int set = r0 >> 14;
    const int bb  = (r0 >> 12) & 3;
    const int l0  = r0 & 4095;
    unsigned char* dst = zn8 + ((size_t)(bb * 2 + set) * 4096 + l0) * 256;
    const int colbase = w * 64 + l15;
#pragma unroll
    for (int mi = 0; mi < 4; ++mi)
#pragma unroll
        for (int reg = 0; reg < 4; ++reg) {
            const int rl = mi * 16 + quad * 4 + reg;
            const float inv = rinv[rl];
#pragma unroll
            for (int ni = 0; ni < 4; ++ni)
                dst[(size_t)rl * 256 + colbase + ni * 16] =
                    f2fp8(acc[mi][ni][reg] * inv);
        }
}

// ---------------------------------------------------------------------------
// FP8 symmetric flash-gram: grid 512 x 256thr (4 waves, 2wm x 2wn).
// Block = (batch, pair p, quarter): pair = row-stripes {p, 63-p}, 65 tiles,
// quarters 17/16/16/16.  Double-buffered 32KB B staging; A-frags (fp8 regs)
// reloaded at the row break.  Row-sums in regs -> atomic flush per stripe.
// Col-sums (symmetry): per off-diag tile, each wave stores its 64-row
// partial for its wm half directly (non-atomic) into plane
// Cc[batch][2*row+wm][8192] -> NO cross-wave combine, ONE barrier/tile.
// final_log reads only planes 0..2*(q>>7)-1 (all written) -> no memset.
// setprio(1) wraps the MFMA cluster.
// ---------------------------------------------------------------------------
#if defined(__has_builtin)
#if __has_builtin(__builtin_amdgcn_mfma_scale_f32_16x16x128_f8f6f4)
#define HAVE_MX 1
#endif
#endif

__global__ __launch_bounds__(256, 2) void gram_fp8_sym_kernel(
    const unsigned char* __restrict__ zn8, float* __restrict__ S,
    float* __restrict__ Cc, float* __restrict__ out)
{
    __shared__ unsigned char lsB[2][32768];   // [buf][kp 0..15][col 0..127][16B]

    const int bx    = blockIdx.x;             // 0..511
    const int xcd   = bx & 7;                 // batch -> XCD pair {2b,2b+1}
    const int batch = xcd >> 1;
    const int sub   = (bx >> 3) * 2 + (xcd & 1);   // 0..127
    const int p     = sub >> 2;               // pair 0..31
    const int qu    = sub & 3;                // quarter
    const int u0    = (qu == 0) ? 0 : 17 + (qu - 1) * 16;
    const int u1    = u0 + ((qu == 0) ? 17 : 16);
    const int ubrk  = 64 - p;                 // first tile index of row 63-p

    const unsigned char* Z = zn8 + (size_t)batch * 2097152;

    const int tid  = threadIdx.x;
    const int w    = tid >> 6;
    const int lane = tid & 63;
    const int wm   = w & 1;                   // 64-row band
    const int wn   = w >> 1;                  // 64-col band
    const int quad = lane >> 4;
    const int l15  = lane & 15;

#define TJ_OF(u)  ((u) < ubrk ? p + (u) : (u) - 1)
#define ROW_OF(u) ((u) < ubrk ? p : 63 - p)

#define STAGE_B(t, buf)                                                       \
    {                                                                         \
        const unsigned char* Bb = Z + (size_t)(t) * 128 * 256;                \
        _Pragma("unroll")                                                     \
        for (int r = 0; r < 8; ++r) {                                         \
            const int c   = w * 8 + r;                                        \
            const int u_  = c * 64 + lane;                                    \
            const int kp  = u_ >> 7;                                          \
            const int col = u_ & 127;                                         \
            gl_lds16(Bb + (size_t)col * 256 + kp * 16,                        \
                     &lsB[buf][(size_t)c * 1024]);                            \
        }                                                                     \
    }

    float rs[4][4];
#pragma unroll
    for (int mi = 0; mi < 4; ++mi)
#pragma unroll
        for (int reg = 0; reg < 4; ++reg)
            rs[mi][reg] = 0.f;
    float dsum = 0.f;

#define FLUSH_RS(rowstripe)                                                   \
    {                                                                         \
        float* Sr = S + (size_t)batch * 8192 + (rowstripe) * 128 + wm * 64;   \
        _Pragma("unroll")                                                     \
        for (int mi = 0; mi < 4; ++mi)                                        \
            _Pragma("unroll")                                                 \
            for (int reg = 0; reg < 4; ++reg) {                               \
                float v = rs[mi][reg];                                        \
                v += __shfl_xor(v, 1); v += __shfl_xor(v, 2);                 \
                v += __shfl_xor(v, 4); v += __shfl_xor(v, 8);                 \
                if (l15 == 0)                                                 \
                    atomicAdd(&Sr[mi * 16 + quad * 4 + reg], v);              \
                rs[mi][reg] = 0.f;                                            \
            }                                                                 \
    }

    int currow = ROW_OF(u0);

#ifdef HAVE_MX
    int8v afr[4][2];
#define LOAD_A(rowstripe)                                                     \
    {                                                                         \
        const unsigned char* Ab = Z + (size_t)((rowstripe) * 128 + wm * 64) * 256; \
        _Pragma("unroll")                                                     \
        for (int mi = 0; mi < 4; ++mi)                                        \
            _Pragma("unroll")                                                 \
            for (int ks = 0; ks < 2; ++ks) {                                  \
                const unsigned char* pA = Ab + (size_t)(mi * 16 + l15) * 256  \
                                          + ks * 128 + quad * 32;             \
                int4v lo = *(const int4v*)pA;                                 \
                int4v hi = *(const int4v*)(pA + 16);                          \
                afr[mi][ks] = __builtin_shufflevector(lo, hi, 0,1,2,3,4,5,6,7); \
            }                                                                 \
    }
#else
    long afr[4][8];
#define LOAD_A(rowstripe)                                                     \
    {                                                                         \
        const unsigned char* Ab = Z + (size_t)((rowstripe) * 128 + wm * 64) * 256; \
        _Pragma("unroll")                                                     \
        for (int mi = 0; mi < 4; ++mi)                                        \
            _Pragma("unroll")                                                 \
            for (int kc = 0; kc < 8; ++kc)                                    \
                afr[mi][kc] = *(const long*)(Ab + (size_t)(mi * 16 + l15) * 256 \
                                             + kc * 32 + quad * 8);           \
    }
#endif

    LOAD_A(currow);
    STAGE_B(TJ_OF(u0), 0);
    __syncthreads();

    for (int ui = u0; ui < u1; ++ui) {
        const int buf = (ui - u0) & 1;
        const int row = ROW_OF(ui);
        const int tj  = TJ_OF(ui);
        if (row != currow) {                  // crossed into row 63-p
            FLUSH_RS(currow);
            LOAD_A(row);
            currow = row;
        }
        if (ui + 1 < u1) STAGE_B(TJ_OF(ui + 1), buf ^ 1);

        float4v acc[4][4];
#pragma unroll
        for (int mi = 0; mi < 4; ++mi)
#pragma unroll
            for (int ni = 0; ni < 4; ++ni)
                acc[mi][ni] = (float4v){0.f, 0.f, 0.f, 0.f};

        const unsigned char* lb = &lsB[buf][0];
        __builtin_amdgcn_s_setprio(1);
#ifdef HAVE_MX
#pragma unroll
        for (int ks = 0; ks < 2; ++ks) {
            const int kp0 = ks * 8 + quad * 2;
            int8v bfv[4];
#pragma unroll
            for (int ni = 0; ni < 4; ++ni) {
                const unsigned char* pB = lb +
                    ((size_t)kp0 * 128 + wn * 64 + ni * 16 + l15) * 16;
                int4v lo = *(const int4v*)pB;
                int4v hi = *(const int4v*)(pB + 2048);   // kp0+1 slot
                bfv[ni] = __builtin_shufflevector(lo, hi, 0,1,2,3,4,5,6,7);
            }
#pragma unroll
            for (int mi = 0; mi < 4; ++mi)
#pragma unroll
                for (int ni = 0; ni < 4; ++ni)
                    acc[mi][ni] = __builtin_amdgcn_mfma_scale_f32_16x16x128_f8f6f4(
                        afr[mi][ks], bfv[ni], acc[mi][ni],
                        0, 0,                     // cbsz=E4M3, blgp=E4M3
                        0, 0x7F7F7F7F,            // scale A = 1.0
                        0, 0x7F7F7F7F);           // scale B = 1.0
        }
#else
#pragma unroll
        for (int kc = 0; kc < 8; ++kc) {
            const int kseg = kc * 4 + quad;
            const int kp   = kseg >> 1;
            const int hf   = kseg & 1;
            long bfv[4];
#pragma unroll
            for (int ni = 0; ni < 4; ++ni)
                bfv[ni] = *(const long*)(lb +
                    ((size_t)kp * 128 + wn * 64 + ni * 16 + l15) * 16 + hf * 8);
#pragma unroll
            for (int mi = 0; mi < 4; ++mi)
#pragma unroll
                for (int ni = 0; ni < 4; ++ni)
                    acc[mi][ni] = __builtin_amdgcn_mfma_f32_16x16x32_fp8_fp8(
                        afr[mi][kc], bfv[ni], acc[mi][ni], 0, 0, 0);
        }
#endif
        __builtin_amdgcn_s_setprio(0);

        // ---- cross tile: extract (q,q+4096) dots (raw acc, BEFORE exp)
        if (tj == row + 32) {
#pragma unroll
            for (int mi = 0; mi < 4; ++mi)
#pragma unroll
                for (int ni = 0; ni < 4; ++ni)
#pragma unroll
                    for (int reg = 0; reg < 4; ++reg) {
                        const int r = wm * 64 + mi * 16 + quad * 4 + reg;
                        const int c = wn * 64 + ni * 16 + l15;
                        if (r == c) dsum += acc[mi][ni][reg];
                    }
        }

        // ---- exp2 in place (acc already = 2*log2e*dot via zn8 scaling)
#pragma unroll
        for (int mi = 0; mi < 4; ++mi)
#pragma unroll
            for (int ni = 0; ni < 4; ++ni)
#pragma unroll
                for (int reg = 0; reg < 4; ++reg)
                    acc[mi][ni][reg] = EXP2F(acc[mi][ni][reg]);

        // ---- row sums accumulate in regs
#pragma unroll
        for (int mi = 0; mi < 4; ++mi)
#pragma unroll
            for (int reg = 0; reg < 4; ++reg)
                rs[mi][reg] += acc[mi][0][reg] + acc[mi][1][reg]
                             + acc[mi][2][reg] + acc[mi][3][reg];

        // ---- col sums (symmetry): per-wave 64-row partial -> own plane
        if (tj > row) {
            float* Cd = Cc + ((size_t)batch * 128 + row * 2 + wm) * 8192
                        + tj * 128 + wn * 64;
#pragma unroll
            for (int ni = 0; ni < 4; ++ni) {
                float s = 0.f;
#pragma unroll
                for (int mi = 0; mi < 4; ++mi)
#pragma unroll
                    for (int reg = 0; reg < 4; ++reg)
                        s += acc[mi][ni][reg];
                s += __shfl_xor(s, 16); s += __shfl_xor(s, 32);
                if (quad == 0)
                    Cd[ni * 16 + l15] = s;
            }
        }
        __syncthreads();                      // single per-tile barrier
    }

    FLUSH_RS(currow);

    // dv = 2*log2e * sum(d);  need -0.5*sum(d) -> factor -0.25*ln2
    {
        float dv = dsum;
        dv += __shfl_xor(dv, 1);  dv += __shfl_xor(dv, 2);
        dv += __shfl_xor(dv, 4);  dv += __shfl_xor(dv, 8);
        dv += __shfl_xor(dv, 16); dv += __shfl_xor(dv, 32);
        if (lane == 0 && dv != 0.f)
            atomicAdd(out, -0.17328680f * dv);
    }
#undef STAGE_B
#undef LOAD_A
#undef FLUSH_RS
#undef TJ_OF
#undef ROW_OF
}

// ---------------------------------------------------------------------------
// final: out += 0.125 * sum_{b,q} log(S[b][q] + sum_{r<2*(q>>7)} Cc[b][r][q] - e^2)
// grid 128 x 256 (one thread per (b,q)).  Only valid (written) planes read.
// ---------------------------------------------------------------------------
__global__ __launch_bounds__(256) void final_log_kernel(
    const float* __restrict__ S, const float* __restrict__ Cc,
    float* __restrict__ out)
{
    __shared__ float red[4];
    const int tid  = threadIdx.x;
    const int w    = tid >> 6;
    const int lane = tid & 63;
    const float E2 = 7.3890560989306495f;

    const int i = blockIdx.x * 256 + tid;     // 0..32767
    const int b = i >> 13;
    const int q = i & 8191;
    float s = S[i];
    const float* Cp = Cc + (size_t)b * 128 * 8192 + q;
    const int np = (q >> 7) * 2;              // planes 0..np-1 are written
    for (int r = 0; r < np; ++r)
        s += Cp[(size_t)r * 8192];
    float acc = logf(s - E2);

    acc += __shfl_xor(acc, 1);  acc += __shfl_xor(acc, 2);
    acc += __shfl_xor(acc, 4);  acc += __shfl_xor(acc, 8);
    acc += __shfl_xor(acc, 16); acc += __shfl_xor(acc, 32);
    if (lane == 0) red[w] = acc;
    __syncthreads();
    if (tid == 0)
        atomicAdd(out, 0.125f * (red[0] + red[1] + red[2] + red[3]));
}

// ---------------------------------------------------------------------------
// Workspace (bytes), total ~25.6 MB:
//   [0,       131072)  S (4*8192 fp32)
//   [131072,  262144)  W1bf
//   [262144,  393216)  W2bf
//   [393216, 17170432) Xbf (bf16, 16.78MB); after fusedproj DEAD ->
//                      aliased by Cc (4*128*8192 fp32 = 16.78MB, no memset:
//                      final reads only written planes)
//   [17170432,25559040) zn8 (fp8, 8.39MB)
// ---------------------------------------------------------------------------
extern "C" void kernel_launch(void* const* d_in, const int* in_sizes, int n_in,
                              void* d_out, int out_size, void* d_ws, size_t ws_size,
                              hipStream_t stream)
{
    const float* X1 = (const float*)d_in[0];
    const float* X2 = (const float*)d_in[1];
    const float* W1 = (const float*)d_in[2];
    const float* b1 = (const float*)d_in[3];
    const float* W2 = (const float*)d_in[4];
    const float* b2 = (const float*)d_in[5];

    char* ws = (char*)d_ws;
    float* S    = (float*)(ws + 0);
    short* W1bf = (short*)(ws + 131072);
    short* W2bf = (short*)(ws + 262144);
    short* Xbf  = (short*)(ws + 393216);
    float* Cc   = (float*)(ws + 393216);      // aliases Xbf (dead after proj)
    unsigned char* zn8 = (unsigned char*)(ws + 17170432);

    hipMemsetAsync(S, 0, 131072, stream);
    hipMemsetAsync(d_out, 0, sizeof(float), stream);

    convW_kernel<<<128, 256, 0, stream>>>(W1, W2, W1bf, W2bf);
    convX_kernel<<<8192, 256, 0, stream>>>(X1, X2, Xbf);
    fusedproj_kernel<<<512, 256, 0, stream>>>(Xbf, W1bf, b1, W2bf, b2, zn8);
    gram_fp8_sym_kernel<<<512, 256, 0, stream>>>(zn8, S, Cc, (float*)d_out);
    final_log_kernel<<<128, 256, 0, stream>>>(S, Cc, (float*)d_out);
}